// Round 1
// baseline (4775.376 us; speedup 1.0000x reference)
//
#include <hip/hip_runtime.h>
#include <math.h>

#define MM 64
#define NN 512
#define DD 300
#define FF 768
#define CTXL 50
#define DOCL 100
#define BODYL 200
#define NHEAD 5
#define HD 60

// ---------------- workspace layout (float offsets) ----------------
static constexpr size_t OFF_MS    = 0;                    // 64*768
static constexpr size_t OFF_MC    = 49152;                // 64*768
static constexpr size_t OFF_TNORM = 98304;                // 512
static constexpr size_t OFF_COSDT = 98816;                // 512
static constexpr size_t OFF_CAND  = 99328;                // 512*300
static constexpr size_t OFF_DOC   = 252928;               // 100*300
static constexpr size_t OFF_COMB  = 282928;               // 512*600
static constexpr size_t OFF_ATTS  = 590128;               // 512
static constexpr size_t OFF_COSST = 590640;               // 64*512
static constexpr size_t OFF_COSCT = 623408;               // 64*512
static constexpr size_t OFF_LOCATT= 656176;               // 64*512
static constexpr size_t OFF_S     = 688944;               // 512
static constexpr size_t OFF_KEEP  = 689456;               // 512
static constexpr size_t OFF_INV   = 689968;               // 512
static constexpr size_t OFF_FAI_A = 690480;               // 512
static constexpr size_t OFF_FAI_B = 690992;               // 512
// total 691504 floats = 2.77 MB

// ---------------- init: title norms, cos_dt, cand/doc gathers, zero s/keep ----
__global__ __launch_bounds__(64) void k_init(
    const float* __restrict__ embed, const float* __restrict__ title,
    const float* __restrict__ bert, const int* __restrict__ cand_ids,
    const int* __restrict__ doc_ids, float* __restrict__ ws) {
  int n = blockIdx.x, t = threadIdx.x;
  float ss = 0.f, dd = 0.f, bb = 0.f;
  for (int j = t; j < FF; j += 64) {
    float tv = title[(size_t)n*FF + j], bv = bert[j];
    ss += tv*tv; dd += tv*bv; bb += bv*bv;
  }
#pragma unroll
  for (int o = 32; o; o >>= 1) {
    ss += __shfl_down(ss, o); dd += __shfl_down(dd, o); bb += __shfl_down(bb, o);
  }
  if (t == 0) {
    float tn = fmaxf(sqrtf(ss), 1e-6f);
    float bn = fmaxf(sqrtf(bb), 1e-6f);
    ws[OFF_TNORM + n] = tn;
    ws[OFF_COSDT + n] = dd / (tn * bn);
  }
  size_t cid = (size_t)cand_ids[n] * DD;
  for (int j = t; j < DD; j += 64) ws[OFF_CAND + (size_t)n*DD + j] = embed[cid + j];
  if (n < DOCL) {
    size_t did = (size_t)doc_ids[n] * DD;
    for (int j = t; j < DD; j += 64) ws[OFF_DOC + (size_t)n*DD + j] = embed[did + j];
  }
  if (n == 0) {
    for (int j = t; j < NN; j += 64) { ws[OFF_S + j] = 0.f; ws[OFF_KEEP + j] = 0.f; }
  }
}

// ---------------- mention surface conv (k=2, L=4 -> 3), relu, mean ----------
__global__ __launch_bounds__(256) void k_ms(
    const float* __restrict__ embed, const int* __restrict__ mention_ids,
    const float* __restrict__ W, const float* __restrict__ b, float* __restrict__ ws) {
  __shared__ float x[4][DD];
  int m = blockIdx.x, t = threadIdx.x;
  for (int i = t; i < 4*DD; i += 256) {
    int r = i / DD, c = i % DD;
    x[r][c] = embed[(size_t)mention_ids[m*4 + r]*DD + c];
  }
  __syncthreads();
  for (int f = t; f < FF; f += 256) {
    const float* w = W + (size_t)f * (DD*2);
    float bb = b[f];
    float acc = 0.f;
#pragma unroll
    for (int tt = 0; tt < 3; ++tt) {
      float y = bb;
      for (int d = 0; d < DD; ++d) {
        float2 wv = *(const float2*)&w[d*2];
        y += wv.x * x[tt][d] + wv.y * x[tt+1][d];
      }
      acc += fmaxf(y, 0.f);
    }
    ws[OFF_MS + (size_t)m*FF + f] = acc * (1.f/3.f);
  }
}

// ---------------- context conv (k=5, L=50 -> 46), relu, mean ----------------
__global__ __launch_bounds__(256) void k_mc(
    const float* __restrict__ embed, const int* __restrict__ context_ids,
    const float* __restrict__ W, const float* __restrict__ b, float* __restrict__ ws) {
  __shared__ float x[CTXL][301];
  __shared__ float red[48][5];
  int m = blockIdx.x, fc = blockIdx.y, t = threadIdx.x;
  for (int i = t; i < CTXL*DD; i += 256) {
    int r = i / DD, c = i % DD;
    x[r][c] = embed[(size_t)context_ids[m*CTXL + r]*DD + c];
  }
  __syncthreads();
  int fi = t / 5, tg = t % 5;
  if (fi < 48) {
    int f = fc*48 + fi;
    const float* w = W + (size_t)f * (DD*5);
    float bb = b[f];
    float acc = 0.f;
    for (int tt = tg; tt < 46; tt += 5) {
      float y = bb;
#pragma unroll
      for (int k = 0; k < 5; ++k) {
        const float* xr = x[tt + k];
        const float* wk = w + k;
        for (int d = 0; d < DD; ++d) y += wk[d*5] * xr[d];
      }
      acc += fmaxf(y, 0.f);
    }
    red[fi][tg] = acc;
  }
  __syncthreads();
  if (t < 48) {
    float a = red[t][0] + red[t][1] + red[t][2] + red[t][3] + red[t][4];
    ws[OFF_MC + (size_t)m*FF + fc*48 + t] = a * (1.f/46.f);
  }
}

// ---------------- cos_st / cos_ct ----------------
__global__ __launch_bounds__(256) void k_cos(
    const float* __restrict__ title, float* __restrict__ ws) {
  __shared__ float a[FF], bv_[FF];
  __shared__ float redA[4], redB[4];
  int m = blockIdx.x, t = threadIdx.x;
  float pa = 0.f, pb = 0.f;
  for (int j = t; j < FF; j += 256) {
    float v = ws[OFF_MS + (size_t)m*FF + j]; a[j] = v; pa += v*v;
    float u = ws[OFF_MC + (size_t)m*FF + j]; bv_[j] = u; pb += u*u;
  }
#pragma unroll
  for (int o = 32; o; o >>= 1) { pa += __shfl_down(pa, o); pb += __shfl_down(pb, o); }
  if ((t & 63) == 0) { redA[t>>6] = pa; redB[t>>6] = pb; }
  __syncthreads();
  float na = fmaxf(sqrtf(redA[0]+redA[1]+redA[2]+redA[3]), 1e-6f);
  float nb = fmaxf(sqrtf(redB[0]+redB[1]+redB[2]+redB[3]), 1e-6f);
  float ia = 1.f / na, ib = 1.f / nb;
  for (int n = t; n < NN; n += 256) {
    const float4* tr = (const float4*)(title + (size_t)n*FF);
    float ds = 0.f, dc = 0.f;
    for (int j = 0; j < FF/4; ++j) {
      float4 tv = tr[j];
      float4 av = *(const float4*)&a[j*4];
      float4 bw = *(const float4*)&bv_[j*4];
      ds += av.x*tv.x + av.y*tv.y + av.z*tv.z + av.w*tv.w;
      dc += bw.x*tv.x + bw.y*tv.y + bw.z*tv.z + bw.w*tv.w;
    }
    float it = 1.f / ws[OFF_TNORM + n];
    ws[OFF_COSST + (size_t)m*NN + n] = ds * ia * it;
    ws[OFF_COSCT + (size_t)m*NN + n] = dc * ib * it;
  }
}

// ---------------- 5-head doc<->body attention, per (n,h) block --------------
__global__ __launch_bounds__(256) void k_att(
    const float* __restrict__ embed, const int* __restrict__ body_ids,
    float* __restrict__ ws) {
  __shared__ __align__(16) float qhT[HD][100];   // [j][q]
  __shared__ __align__(16) float khT[HD][204];   // [j][k]
  __shared__ __align__(16) float E[DOCL][208];   // exp(S)[q][k]
  __shared__ float rs_[DOCL];
  __shared__ float cs_[BODYL];
  __shared__ float mred[4][64];
  int n = blockIdx.x, h = blockIdx.y, t = threadIdx.x;
  const float scale = 0.1290994448735806f; // 1/sqrt(60)
  const float* doc = ws + OFF_DOC;
  for (int i = t; i < DOCL*64; i += 256) {
    int q = i >> 6, j = i & 63;
    if (j < HD) qhT[j][q] = doc[q*DD + h*HD + j];
  }
  const int* bids = body_ids + n*BODYL;
  for (int i = t; i < BODYL*64; i += 256) {
    int k = i >> 6, j = i & 63;
    if (j < HD) khT[j][k] = embed[(size_t)bids[k]*DD + h*HD + j];
  }
  __syncthreads();
  // E = exp(S*scale), 4x4 register tiles
  for (int e = t; e < 25*50; e += 256) {
    int qt = e / 50, kt = e % 50;
    int q0 = qt*4, k0 = kt*4;
    float acc[4][4];
#pragma unroll
    for (int aq = 0; aq < 4; ++aq)
#pragma unroll
      for (int ak = 0; ak < 4; ++ak) acc[aq][ak] = 0.f;
    for (int j = 0; j < HD; ++j) {
      float4 qv = *(const float4*)&qhT[j][q0];
      float4 kv = *(const float4*)&khT[j][k0];
      float qa[4] = {qv.x, qv.y, qv.z, qv.w};
      float ka[4] = {kv.x, kv.y, kv.z, kv.w};
#pragma unroll
      for (int aq = 0; aq < 4; ++aq)
#pragma unroll
        for (int ak = 0; ak < 4; ++ak) acc[aq][ak] += qa[aq]*ka[ak];
    }
#pragma unroll
    for (int aq = 0; aq < 4; ++aq) {
      float4 ev;
      ev.x = __expf(acc[aq][0]*scale);
      ev.y = __expf(acc[aq][1]*scale);
      ev.z = __expf(acc[aq][2]*scale);
      ev.w = __expf(acc[aq][3]*scale);
      *(float4*)&E[q0+aq][k0] = ev;
    }
  }
  __syncthreads();
  for (int q = t; q < DOCL; q += 256) {
    float s = 0.f;
    for (int k4 = 0; k4 < 50; ++k4) {
      float4 v = *(const float4*)&E[q][k4*4];
      s += v.x + v.y + v.z + v.w;
    }
    rs_[q] = 1.f / s;
  }
  for (int k = t; k < BODYL; k += 256) {
    float s = 0.f;
    for (int q = 0; q < DOCL; ++q) s += E[q][k];
    cs_[k] = 1.f / s;
  }
  __syncthreads();
  int jj = t & 63, grp = t >> 6;
  // att_db: softmax over k, weighted sum of kh, max over q
  {
    float acc[25];
#pragma unroll
    for (int i = 0; i < 25; ++i) acc[i] = 0.f;
    if (jj < HD) {
      for (int k0 = 0; k0 < BODYL; k0 += 4) {
        float4 khv = *(const float4*)&khT[jj][k0];
#pragma unroll
        for (int i = 0; i < 25; ++i) {
          float4 ev = *(const float4*)&E[grp*25 + i][k0];
          acc[i] += ev.x*khv.x + ev.y*khv.y + ev.z*khv.z + ev.w*khv.w;
        }
      }
    }
    float mx = -1e30f;
#pragma unroll
    for (int i = 0; i < 25; ++i) mx = fmaxf(mx, acc[i]*rs_[grp*25 + i]);
    mred[grp][jj] = mx;
  }
  __syncthreads();
  if (t < HD) {
    float mx = fmaxf(fmaxf(mred[0][t], mred[1][t]), fmaxf(mred[2][t], mred[3][t]));
    ws[OFF_COMB + (size_t)n*600 + h*HD + t] = mx;
  }
  __syncthreads();
  // att_bd: softmax over q, weighted sum of qh, max over k
  {
    float acc[52];
#pragma unroll
    for (int i = 0; i < 52; ++i) acc[i] = 0.f;
    int kbase = grp*52;
    if (jj < HD) {
      for (int q = 0; q < DOCL; ++q) {
        float qv = qhT[jj][q];
#pragma unroll
        for (int i0 = 0; i0 < 52; i0 += 4) {
          float4 ev = *(const float4*)&E[q][kbase + i0];
          acc[i0+0] += ev.x*qv; acc[i0+1] += ev.y*qv;
          acc[i0+2] += ev.z*qv; acc[i0+3] += ev.w*qv;
        }
      }
    }
    float mx = -1e30f;
#pragma unroll
    for (int i = 0; i < 52; ++i) {
      int k = kbase + i;
      if (k < BODYL) mx = fmaxf(mx, acc[i]*cs_[k]);
    }
    mred[grp][jj] = mx;
  }
  __syncthreads();
  if (t < HD) {
    float mx = fmaxf(fmaxf(mred[0][t], mred[1][t]), fmaxf(mred[2][t], mred[3][t]));
    ws[OFF_COMB + (size_t)n*600 + 300 + h*HD + t] = mx;
  }
}

// ---------------- local context attention: max_t ctx.cand / sqrt(300) -------
__global__ __launch_bounds__(256) void k_local(
    const float* __restrict__ embed, const int* __restrict__ context_ids,
    float* __restrict__ ws) {
  __shared__ __align__(16) float x[CTXL][304];
  __shared__ float red[2][128];
  int m = blockIdx.x, nc = blockIdx.y, t = threadIdx.x;
  for (int i = t; i < CTXL*DD; i += 256) {
    int r = i / DD, c = i % DD;
    x[r][c] = embed[(size_t)context_ids[m*CTXL + r]*DD + c];
  }
  __syncthreads();
  int nl = t & 127, half = t >> 7;
  int n = nc*128 + nl;
  const float4* cr = (const float4*)(ws + OFF_CAND + (size_t)n*DD);
  float acc[25];
#pragma unroll
  for (int i = 0; i < 25; ++i) acc[i] = 0.f;
  for (int d4 = 0; d4 < 75; ++d4) {
    float4 cv = cr[d4];
#pragma unroll
    for (int i = 0; i < 25; ++i) {
      float4 xv = *(const float4*)&x[half*25 + i][d4*4];
      acc[i] += xv.x*cv.x + xv.y*cv.y + xv.z*cv.z + xv.w*cv.w;
    }
  }
  float mx = -1e30f;
#pragma unroll
  for (int i = 0; i < 25; ++i) mx = fmaxf(mx, acc[i]);
  red[half][nl] = mx;
  __syncthreads();
  if (t < 128) {
    float v = fmaxf(red[0][t], red[1][t]) * 0.05773502691896258f; // 1/sqrt(300)
    ws[OFF_LOCATT + (size_t)m*NN + nc*128 + t] = v;
  }
}

// ---------------- attention MLP -> att_score ----------------
__global__ __launch_bounds__(256) void k_mlp(
    const float* __restrict__ W1, const float* __restrict__ b1,
    const float* __restrict__ W2, const float* __restrict__ b2,
    float* __restrict__ ws) {
  __shared__ float comb8[8][600];
  __shared__ float acc8[8];
  int b = blockIdx.x, t = threadIdx.x;
  int n0 = b*8;
  for (int i = t; i < 8*600; i += 256)
    comb8[i/600][i%600] = ws[OFF_COMB + (size_t)(n0 + i/600)*600 + (i%600)];
  if (t < 8) acc8[t] = 0.f;
  __syncthreads();
  float psum[8];
#pragma unroll
  for (int nn2 = 0; nn2 < 8; ++nn2) psum[nn2] = 0.f;
  for (int j = t; j < 300; j += 256) {
    float hh[8];
#pragma unroll
    for (int nn2 = 0; nn2 < 8; ++nn2) hh[nn2] = b1[j];
    for (int i = 0; i < 600; ++i) {
      float w = W1[(size_t)i*300 + j];
#pragma unroll
      for (int nn2 = 0; nn2 < 8; ++nn2) hh[nn2] += comb8[nn2][i]*w;
    }
    float w2 = W2[j];
#pragma unroll
    for (int nn2 = 0; nn2 < 8; ++nn2) psum[nn2] += fmaxf(hh[nn2], 0.f)*w2;
  }
#pragma unroll
  for (int nn2 = 0; nn2 < 8; ++nn2) atomicAdd(&acc8[nn2], psum[nn2]);
  __syncthreads();
  if (t < 8) {
    float v = acc8[t] + b2[0];
    ws[OFF_ATTS + n0 + t] = 1.f / (1.f + __expf(-v));
  }
}

// ---------------- per-mention scoring: raw -> z -> softmax -> s, keep -------
__device__ __forceinline__ float bsum512(float v, float* red) {
  int t = threadIdx.x;
#pragma unroll
  for (int o = 32; o; o >>= 1) v += __shfl_down(v, o);
  __syncthreads();
  if ((t & 63) == 0) red[t>>6] = v;
  __syncthreads();
  float s = 0.f;
#pragma unroll
  for (int i = 0; i < 8; ++i) s += red[i];
  return s;
}
__device__ __forceinline__ float bmax512(float v, float* red) {
  int t = threadIdx.x;
#pragma unroll
  for (int o = 32; o; o >>= 1) v = fmaxf(v, __shfl_down(v, o));
  __syncthreads();
  if ((t & 63) == 0) red[t>>6] = v;
  __syncthreads();
  float s = -INFINITY;
#pragma unroll
  for (int i = 0; i < 8; ++i) s = fmaxf(s, red[i]);
  return s;
}

__global__ __launch_bounds__(512) void k_score(
    const float* __restrict__ hand, const float* __restrict__ m2c,
    const float* __restrict__ llW, const float* __restrict__ llb,
    const float* __restrict__ me, float* __restrict__ ws) {
  __shared__ float red[8];
  __shared__ float rv[512];
  __shared__ int ri[512];
  int m = blockIdx.x, t = threadIdx.x;
  float mask = me[(size_t)m*NN + t];
  float raw = llW[0]*hand[t] + llW[1]*m2c[t] + llW[2]*ws[OFF_LOCATT + (size_t)m*NN + t]
            + llW[3]*ws[OFF_ATTS + t] + llW[4]*ws[OFF_COSST + (size_t)m*NN + t]
            + llW[5]*ws[OFF_COSDT + t] + llW[6]*ws[OFF_COSCT + (size_t)m*NN + t] + llb[0];
  float cnt = bsum512(mask, red);
  float mean = bsum512(raw*mask, red) / cnt;
  float dv = raw - mean;
  float var = bsum512(dv*dv*mask, red) / (cnt - 1.f);
  float z = dv / sqrtf(var);
  float zm = (mask > 0.f) ? z : -INFINITY;
  float mx = bmax512(zm, red);
  float e = (mask > 0.f) ? __expf(zm - mx) : 0.f;
  float ssum = bsum512(e, red);
  float sm = e / ssum * mask;
  atomicAdd(&ws[OFF_S + t], sm);
  // top-3 (ordering of sm == ordering of zm), lowest-index tie-break
  bool excl = false;
  for (int r = 0; r < 3; ++r) {
    rv[t] = excl ? -INFINITY : zm;
    ri[t] = t;
    __syncthreads();
    for (int off = 256; off; off >>= 1) {
      if (t < off) {
        float bb = rv[t+off]; int ib = ri[t+off];
        if (bb > rv[t] || (bb == rv[t] && ib < ri[t])) { rv[t] = bb; ri[t] = ib; }
      }
      __syncthreads();
    }
    int widx = ri[0];
    __syncthreads();
    if (t == 0) ws[OFF_KEEP + widx] = 1.f;
    if (t == widx) excl = true;
  }
}

// ---------------- SR row sums -> inv, init fai = s ----------------
__global__ __launch_bounds__(512) void k_grs(
    const float* __restrict__ esr, const float* __restrict__ eee,
    float* __restrict__ ws) {
  __shared__ float keep_l[NN];
  int b = blockIdx.x, t = threadIdx.x;
  keep_l[t] = ws[OFF_KEEP + t];
  __syncthreads();
  int lane = t & 63, w = t >> 6;
  int r = b*8 + w;
  float p = 0.f;
  for (int j = lane; j < NN; j += 64)
    p += esr[(size_t)r*NN + j] * eee[(size_t)r*NN + j] * keep_l[j];
#pragma unroll
  for (int o = 32; o; o >>= 1) p += __shfl_down(p, o);
  if (lane == 0) {
    ws[OFF_INV + r] = (fabsf(p) < 1e-6f) ? 1.f : 1.f/p;
    ws[OFF_FAI_A + r] = ws[OFF_S + r];
  }
}

// ---------------- one power-iteration step (guarded by it<K) ----------------
__global__ __launch_bounds__(512) void k_giter(
    const float* __restrict__ esr, const float* __restrict__ eee,
    const float* __restrict__ lamda, const int* __restrict__ rk,
    const float* __restrict__ fin, float* __restrict__ fout,
    const float* __restrict__ wsro, int it) {
  int b = blockIdx.x, t = threadIdx.x;
  int K = rk[0];
  if (it >= K) {
    if (t < 8) fout[b*8 + t] = fin[b*8 + t];
    return;
  }
  __shared__ float g[NN];
  __shared__ float red[8][65];
  g[t] = fin[t] * wsro[OFF_INV + t];
  __syncthreads();
  float lam = lamda[0];
  int jl = t & 7, ig = t >> 3;
  int j = b*8 + jl;
  float p = 0.f;
  for (int i = ig; i < NN; i += 64)
    p += g[i] * esr[(size_t)i*NN + j] * eee[(size_t)i*NN + j];
  red[jl][ig] = p;
  __syncthreads();
  if (t < 8) {
    float acc = 0.f;
    for (int i = 0; i < 64; ++i) acc += red[t][i];
    int jj = b*8 + t;
    fout[jj] = (1.f - lam) * wsro[OFF_KEEP + jj] * acc + lam * wsro[OFF_S + jj];
  }
}

// ---------------- final outputs ----------------
__global__ __launch_bounds__(512) void k_gout(
    const float* __restrict__ me, const float* __restrict__ ws, float* __restrict__ out) {
  int m = blockIdx.x, t = threadIdx.x;
  float fai = ws[OFF_FAI_A + t];
  if (m == 0) { out[t] = ws[OFF_S + t]; out[NN + t] = fai; }
  out[2*NN + (size_t)m*NN + t] = me[(size_t)m*NN + t] * fai;
}

extern "C" void kernel_launch(void* const* d_in, const int* in_sizes, int n_in,
                              void* d_out, int out_size, void* d_ws, size_t ws_size,
                              hipStream_t stream) {
  const float* embed   = (const float*)d_in[0];
  const float* W_ms    = (const float*)d_in[1];
  const float* b_ms    = (const float*)d_in[2];
  const float* W_mc    = (const float*)d_in[3];
  const float* b_mc    = (const float*)d_in[4];
  const float* att_W1  = (const float*)d_in[5];
  const float* att_b1  = (const float*)d_in[6];
  const float* att_W2  = (const float*)d_in[7];
  const float* att_b2  = (const float*)d_in[8];
  const float* ll_W    = (const float*)d_in[9];
  const float* ll_b    = (const float*)d_in[10];
  const float* lamda   = (const float*)d_in[11];
  const int* mention_ids = (const int*)d_in[12];
  const int* context_ids = (const int*)d_in[13];
  const int* doc_ids     = (const int*)d_in[14];
  const int* body_ids    = (const int*)d_in[15];
  const int* cand_ids    = (const int*)d_in[16];
  const float* title   = (const float*)d_in[17];
  const float* bert    = (const float*)d_in[18];
  const float* hand    = (const float*)d_in[19];
  const float* m2c     = (const float*)d_in[20];
  const float* me      = (const float*)d_in[21];
  const float* eee     = (const float*)d_in[22];
  const float* esr     = (const float*)d_in[23];
  const int* rk        = (const int*)d_in[24];
  float* ws  = (float*)d_ws;
  float* out = (float*)d_out;

  hipLaunchKernelGGL(k_init, dim3(NN), dim3(64), 0, stream, embed, title, bert, cand_ids, doc_ids, ws);
  hipLaunchKernelGGL(k_ms, dim3(MM), dim3(256), 0, stream, embed, mention_ids, W_ms, b_ms, ws);
  hipLaunchKernelGGL(k_mc, dim3(MM, 16), dim3(256), 0, stream, embed, context_ids, W_mc, b_mc, ws);
  hipLaunchKernelGGL(k_cos, dim3(MM), dim3(256), 0, stream, title, ws);
  hipLaunchKernelGGL(k_att, dim3(NN, NHEAD), dim3(256), 0, stream, embed, body_ids, ws);
  hipLaunchKernelGGL(k_local, dim3(MM, 4), dim3(256), 0, stream, embed, context_ids, ws);
  hipLaunchKernelGGL(k_mlp, dim3(64), dim3(256), 0, stream, att_W1, att_b1, att_W2, att_b2, ws);
  hipLaunchKernelGGL(k_score, dim3(MM), dim3(512), 0, stream, hand, m2c, ll_W, ll_b, me, ws);
  hipLaunchKernelGGL(k_grs, dim3(64), dim3(512), 0, stream, esr, eee, ws);
  float* fa = ws + OFF_FAI_A;
  float* fb = ws + OFF_FAI_B;
  for (int it = 0; it < 8; ++it) {
    hipLaunchKernelGGL(k_giter, dim3(64), dim3(512), 0, stream, esr, eee, lamda, rk,
                       (it & 1) ? fb : fa, (it & 1) ? fa : fb, ws, it);
  }
  hipLaunchKernelGGL(k_gout, dim3(MM), dim3(512), 0, stream, me, ws, out);
}

// Round 2
// 1641.522 us; speedup vs baseline: 2.9091x; 2.9091x over previous
//
#include <hip/hip_runtime.h>
#include <math.h>

#define MM 64
#define NN 512
#define DD 300
#define FF 768
#define CTXL 50
#define DOCL 100
#define BODYL 200
#define NHEAD 5
#define HD 60

// ---------------- workspace layout (float offsets) ----------------
static constexpr size_t OFF_MS    = 0;                    // 64*768
static constexpr size_t OFF_MC    = 49152;                // 64*768
static constexpr size_t OFF_TNORM = 98304;                // 512
static constexpr size_t OFF_COSDT = 98816;                // 512
static constexpr size_t OFF_CAND  = 99328;                // 512*300
static constexpr size_t OFF_DOC   = 252928;               // 100*300
static constexpr size_t OFF_COMB  = 282928;               // 512*600
static constexpr size_t OFF_ATTS  = 590128;               // 512
static constexpr size_t OFF_COSST = 590640;               // 64*512
static constexpr size_t OFF_COSCT = 623408;               // 64*512
static constexpr size_t OFF_LOCATT= 656176;               // 64*512
static constexpr size_t OFF_S     = 688944;               // 512
static constexpr size_t OFF_KEEP  = 689456;               // 512
static constexpr size_t OFF_INV   = 689968;               // 512
static constexpr size_t OFF_FAI_A = 690480;               // 512
static constexpr size_t OFF_FAI_B = 690992;               // 512
static constexpr size_t OFF_CTXG  = 691504;               // 64*52*300 (2 pad rows/mention)
static constexpr size_t OFF_WT    = 1689904;              // 1500*768 transposed W_mc
// total 2841904 floats = 11.4 MB

// ---------------- init: title norms, cos_dt, cand/doc gathers, zero s/keep ----
__global__ __launch_bounds__(64) void k_init(
    const float* __restrict__ embed, const float* __restrict__ title,
    const float* __restrict__ bert, const int* __restrict__ cand_ids,
    const int* __restrict__ doc_ids, float* __restrict__ ws) {
  int n = blockIdx.x, t = threadIdx.x;
  float ss = 0.f, dd = 0.f, bb = 0.f;
  for (int j = t; j < FF; j += 64) {
    float tv = title[(size_t)n*FF + j], bv = bert[j];
    ss += tv*tv; dd += tv*bv; bb += bv*bv;
  }
#pragma unroll
  for (int o = 32; o; o >>= 1) {
    ss += __shfl_down(ss, o); dd += __shfl_down(dd, o); bb += __shfl_down(bb, o);
  }
  if (t == 0) {
    float tn = fmaxf(sqrtf(ss), 1e-6f);
    float bn = fmaxf(sqrtf(bb), 1e-6f);
    ws[OFF_TNORM + n] = tn;
    ws[OFF_COSDT + n] = dd / (tn * bn);
  }
  size_t cid = (size_t)cand_ids[n] * DD;
  for (int j = t; j < DD; j += 64) ws[OFF_CAND + (size_t)n*DD + j] = embed[cid + j];
  if (n < DOCL) {
    size_t did = (size_t)doc_ids[n] * DD;
    for (int j = t; j < DD; j += 64) ws[OFF_DOC + (size_t)n*DD + j] = embed[did + j];
  }
  if (n == 0) {
    for (int j = t; j < NN; j += 64) { ws[OFF_S + j] = 0.f; ws[OFF_KEEP + j] = 0.f; }
  }
}

// ---------------- gather ctx embeddings once: ctxg[m][0..49]=emb, [50..51]=0 --
__global__ __launch_bounds__(256) void k_gather(
    const float* __restrict__ embed, const int* __restrict__ context_ids,
    float* __restrict__ ws) {
  int m = blockIdx.x, t = threadIdx.x;
  float* dst = ws + OFF_CTXG + (size_t)m*52*DD;
  for (int i = t; i < 52*DD; i += 256) {
    int r = i / DD, c = i - r*DD;
    dst[i] = (r < CTXL) ? embed[(size_t)context_ids[m*CTXL + r]*DD + c] : 0.f;
  }
}

// ---------------- transpose W_mc [f][d][k] -> Wt[k*300+d][f] ----------------
__global__ __launch_bounds__(256) void k_wt(
    const float* __restrict__ W, float* __restrict__ ws) {
  int kd = blockIdx.x;                  // = k*300 + d
  int k = kd / DD, d = kd - k*DD;
  int t = threadIdx.x;
  float* dst = ws + OFF_WT + (size_t)kd*FF;
  for (int f = t; f < FF; f += 256) dst[f] = W[(size_t)f*(DD*5) + d*5 + k];
}

// ---------------- mention surface conv (k=2, L=4 -> 3), relu, mean ----------
__global__ __launch_bounds__(256) void k_ms(
    const float* __restrict__ embed, const int* __restrict__ mention_ids,
    const float* __restrict__ W, const float* __restrict__ b, float* __restrict__ ws) {
  __shared__ float x[4][DD];
  int m = blockIdx.x, t = threadIdx.x;
  for (int i = t; i < 4*DD; i += 256) {
    int r = i / DD, c = i % DD;
    x[r][c] = embed[(size_t)mention_ids[m*4 + r]*DD + c];
  }
  __syncthreads();
  for (int f = t; f < FF; f += 256) {
    const float* w = W + (size_t)f * (DD*2);
    float bb = b[f];
    float acc = 0.f;
#pragma unroll
    for (int tt = 0; tt < 3; ++tt) {
      float y = bb;
      for (int d = 0; d < DD; ++d) {
        float2 wv = *(const float2*)&w[d*2];
        y += wv.x * x[tt][d] + wv.y * x[tt+1][d];
      }
      acc += fmaxf(y, 0.f);
    }
    ws[OFF_MS + (size_t)m*FF + f] = acc * (1.f/3.f);
  }
}

// ---------------- context conv as tiled GEMM --------------------------------
// rows: 48 per mention (tt 0..45 valid, 46/47 pad), cols: 128 filters.
// K = 1500 = 5 taps x 300 dims, chunked 30 x 50 (chunk stays within one tap).
__global__ __launch_bounds__(256) void k_mc_gemm(
    const float* __restrict__ b_mc, float* __restrict__ ws) {
  __shared__ float As[50][49];     // [kj][row], +1 pad -> conflict-free
  __shared__ float Bs[50][128];    // [kj][f]
  int m = blockIdx.x, f0 = blockIdx.y * 128, t = threadIdx.x;
  int tr = t >> 4, tc = t & 15;
  const float* ctxm = ws + OFF_CTXG + (size_t)m*52*DD;
  const float4* wt4 = (const float4*)(ws + OFF_WT);
  float acc[3][8];
#pragma unroll
  for (int r = 0; r < 3; ++r)
#pragma unroll
    for (int j = 0; j < 8; ++j) acc[r][j] = 0.f;

  for (int chunk = 0; chunk < 30; ++chunk) {
    int k = chunk / 6, dc = (chunk - k*6) * 50;
    for (int i = t; i < 48*50; i += 256) {
      int row = i / 50, kj = i - row*50;
      As[kj][row] = ctxm[(row + k)*DD + dc + kj];
    }
    for (int i = t; i < 1600; i += 256) {
      int kj = i >> 5, fq = i & 31;
      *(float4*)&Bs[kj][fq*4] = wt4[((size_t)(k*DD + dc + kj)*FF + f0 + fq*4) >> 2];
    }
    __syncthreads();
#pragma unroll 2
    for (int kj = 0; kj < 50; ++kj) {
      float a0 = As[kj][tr], a1 = As[kj][tr+16], a2 = As[kj][tr+32];
      float4 b0 = *(const float4*)&Bs[kj][tc*8];
      float4 b1 = *(const float4*)&Bs[kj][tc*8+4];
      float bb[8] = {b0.x,b0.y,b0.z,b0.w,b1.x,b1.y,b1.z,b1.w};
#pragma unroll
      for (int j = 0; j < 8; ++j) {
        acc[0][j] += a0*bb[j]; acc[1][j] += a1*bb[j]; acc[2][j] += a2*bb[j];
      }
    }
    __syncthreads();
  }
  // bias + relu + mean over tt<46, reduce across tr groups via LDS
  float bv[8], p[8];
#pragma unroll
  for (int j = 0; j < 8; ++j) { bv[j] = b_mc[f0 + tc*8 + j]; p[j] = 0.f; }
#pragma unroll
  for (int rr = 0; rr < 3; ++rr) {
    int row = tr + 16*rr;
    if (row < 46) {
#pragma unroll
      for (int j = 0; j < 8; ++j) p[j] += fmaxf(acc[rr][j] + bv[j], 0.f);
    }
  }
  float* red = &Bs[0][0];
#pragma unroll
  for (int j = 0; j < 8; ++j) red[tr*128 + tc*8 + j] = p[j];
  __syncthreads();
  if (t < 128) {
    float s = 0.f;
#pragma unroll
    for (int i = 0; i < 16; ++i) s += red[i*128 + t];
    ws[OFF_MC + (size_t)m*FF + f0 + t] = s * (1.f/46.f);
  }
}

// ---------------- cos_st / cos_ct ----------------
__global__ __launch_bounds__(256) void k_cos(
    const float* __restrict__ title, float* __restrict__ ws) {
  __shared__ float a[FF], bv_[FF];
  __shared__ float redA[4], redB[4];
  int m = blockIdx.x, t = threadIdx.x;
  float pa = 0.f, pb = 0.f;
  for (int j = t; j < FF; j += 256) {
    float v = ws[OFF_MS + (size_t)m*FF + j]; a[j] = v; pa += v*v;
    float u = ws[OFF_MC + (size_t)m*FF + j]; bv_[j] = u; pb += u*u;
  }
#pragma unroll
  for (int o = 32; o; o >>= 1) { pa += __shfl_down(pa, o); pb += __shfl_down(pb, o); }
  if ((t & 63) == 0) { redA[t>>6] = pa; redB[t>>6] = pb; }
  __syncthreads();
  float na = fmaxf(sqrtf(redA[0]+redA[1]+redA[2]+redA[3]), 1e-6f);
  float nb = fmaxf(sqrtf(redB[0]+redB[1]+redB[2]+redB[3]), 1e-6f);
  float ia = 1.f / na, ib = 1.f / nb;
  for (int n = t; n < NN; n += 256) {
    const float4* tr = (const float4*)(title + (size_t)n*FF);
    float ds = 0.f, dc = 0.f;
    for (int j = 0; j < FF/4; ++j) {
      float4 tv = tr[j];
      float4 av = *(const float4*)&a[j*4];
      float4 bw = *(const float4*)&bv_[j*4];
      ds += av.x*tv.x + av.y*tv.y + av.z*tv.z + av.w*tv.w;
      dc += bw.x*tv.x + bw.y*tv.y + bw.z*tv.z + bw.w*tv.w;
    }
    float it = 1.f / ws[OFF_TNORM + n];
    ws[OFF_COSST + (size_t)m*NN + n] = ds * ia * it;
    ws[OFF_COSCT + (size_t)m*NN + n] = dc * ib * it;
  }
}

// ---------------- 5-head doc<->body attention, per (n,h) block --------------
__global__ __launch_bounds__(256) void k_att(
    const float* __restrict__ embed, const int* __restrict__ body_ids,
    float* __restrict__ ws) {
  __shared__ __align__(16) float qhT[HD][100];   // [j][q]
  __shared__ __align__(16) float khT[HD][204];   // [j][k]
  __shared__ __align__(16) float E[DOCL][208];   // exp(S)[q][k]
  __shared__ float rs_[DOCL];
  __shared__ float cs_[BODYL];
  __shared__ float mred[4][64];
  int n = blockIdx.x, h = blockIdx.y, t = threadIdx.x;
  const float scale = 0.1290994448735806f; // 1/sqrt(60)
  const float* doc = ws + OFF_DOC;
  for (int i = t; i < DOCL*64; i += 256) {
    int q = i >> 6, j = i & 63;
    if (j < HD) qhT[j][q] = doc[q*DD + h*HD + j];
  }
  const int* bids = body_ids + n*BODYL;
  for (int i = t; i < BODYL*64; i += 256) {
    int k = i >> 6, j = i & 63;
    if (j < HD) khT[j][k] = embed[(size_t)bids[k]*DD + h*HD + j];
  }
  __syncthreads();
  // E = exp(S*scale), 4x4 register tiles
  for (int e = t; e < 25*50; e += 256) {
    int qt = e / 50, kt = e % 50;
    int q0 = qt*4, k0 = kt*4;
    float acc[4][4];
#pragma unroll
    for (int aq = 0; aq < 4; ++aq)
#pragma unroll
      for (int ak = 0; ak < 4; ++ak) acc[aq][ak] = 0.f;
    for (int j = 0; j < HD; ++j) {
      float4 qv = *(const float4*)&qhT[j][q0];
      float4 kv = *(const float4*)&khT[j][k0];
      float qa[4] = {qv.x, qv.y, qv.z, qv.w};
      float ka[4] = {kv.x, kv.y, kv.z, kv.w};
#pragma unroll
      for (int aq = 0; aq < 4; ++aq)
#pragma unroll
        for (int ak = 0; ak < 4; ++ak) acc[aq][ak] += qa[aq]*ka[ak];
    }
#pragma unroll
    for (int aq = 0; aq < 4; ++aq) {
      float4 ev;
      ev.x = __expf(acc[aq][0]*scale);
      ev.y = __expf(acc[aq][1]*scale);
      ev.z = __expf(acc[aq][2]*scale);
      ev.w = __expf(acc[aq][3]*scale);
      *(float4*)&E[q0+aq][k0] = ev;
    }
  }
  __syncthreads();
  for (int q = t; q < DOCL; q += 256) {
    float s = 0.f;
    for (int k4 = 0; k4 < 50; ++k4) {
      float4 v = *(const float4*)&E[q][k4*4];
      s += v.x + v.y + v.z + v.w;
    }
    rs_[q] = 1.f / s;
  }
  for (int k = t; k < BODYL; k += 256) {
    float s = 0.f;
    for (int q = 0; q < DOCL; ++q) s += E[q][k];
    cs_[k] = 1.f / s;
  }
  __syncthreads();
  int jj = t & 63, grp = t >> 6;
  // att_db: softmax over k, weighted sum of kh, max over q
  {
    float acc[25];
#pragma unroll
    for (int i = 0; i < 25; ++i) acc[i] = 0.f;
    if (jj < HD) {
      for (int k0 = 0; k0 < BODYL; k0 += 4) {
        float4 khv = *(const float4*)&khT[jj][k0];
#pragma unroll
        for (int i = 0; i < 25; ++i) {
          float4 ev = *(const float4*)&E[grp*25 + i][k0];
          acc[i] += ev.x*khv.x + ev.y*khv.y + ev.z*khv.z + ev.w*khv.w;
        }
      }
    }
    float mx = -1e30f;
#pragma unroll
    for (int i = 0; i < 25; ++i) mx = fmaxf(mx, acc[i]*rs_[grp*25 + i]);
    mred[grp][jj] = mx;
  }
  __syncthreads();
  if (t < HD) {
    float mx = fmaxf(fmaxf(mred[0][t], mred[1][t]), fmaxf(mred[2][t], mred[3][t]));
    ws[OFF_COMB + (size_t)n*600 + h*HD + t] = mx;
  }
  __syncthreads();
  // att_bd: softmax over q, weighted sum of qh, max over k
  {
    float acc[52];
#pragma unroll
    for (int i = 0; i < 52; ++i) acc[i] = 0.f;
    int kbase = grp*52;
    if (jj < HD) {
      for (int q = 0; q < DOCL; ++q) {
        float qv = qhT[jj][q];
#pragma unroll
        for (int i0 = 0; i0 < 52; i0 += 4) {
          float4 ev = *(const float4*)&E[q][kbase + i0];
          acc[i0+0] += ev.x*qv; acc[i0+1] += ev.y*qv;
          acc[i0+2] += ev.z*qv; acc[i0+3] += ev.w*qv;
        }
      }
    }
    float mx = -1e30f;
#pragma unroll
    for (int i = 0; i < 52; ++i) {
      int k = kbase + i;
      if (k < BODYL) mx = fmaxf(mx, acc[i]*cs_[k]);
    }
    mred[grp][jj] = mx;
  }
  __syncthreads();
  if (t < HD) {
    float mx = fmaxf(fmaxf(mred[0][t], mred[1][t]), fmaxf(mred[2][t], mred[3][t]));
    ws[OFF_COMB + (size_t)n*600 + 300 + h*HD + t] = mx;
  }
}

// ---------------- local context attention: max_t ctx.cand / sqrt(300) -------
__global__ __launch_bounds__(256) void k_local(
    float* __restrict__ ws) {
  __shared__ __align__(16) float x[CTXL][304];
  __shared__ float red[2][128];
  int m = blockIdx.x, nc = blockIdx.y, t = threadIdx.x;
  const float* ctxm = ws + OFF_CTXG + (size_t)m*52*DD;
  for (int i = t; i < CTXL*DD; i += 256) {
    int r = i / DD, c = i % DD;
    x[r][c] = ctxm[i];
  }
  __syncthreads();
  int nl = t & 127, half = t >> 7;
  int n = nc*128 + nl;
  const float4* cr = (const float4*)(ws + OFF_CAND + (size_t)n*DD);
  float acc[25];
#pragma unroll
  for (int i = 0; i < 25; ++i) acc[i] = 0.f;
  for (int d4 = 0; d4 < 75; ++d4) {
    float4 cv = cr[d4];
#pragma unroll
    for (int i = 0; i < 25; ++i) {
      float4 xv = *(const float4*)&x[half*25 + i][d4*4];
      acc[i] += xv.x*cv.x + xv.y*cv.y + xv.z*cv.z + xv.w*cv.w;
    }
  }
  float mx = -1e30f;
#pragma unroll
  for (int i = 0; i < 25; ++i) mx = fmaxf(mx, acc[i]);
  red[half][nl] = mx;
  __syncthreads();
  if (t < 128) {
    float v = fmaxf(red[0][t], red[1][t]) * 0.05773502691896258f; // 1/sqrt(300)
    ws[OFF_LOCATT + (size_t)m*NN + nc*128 + t] = v;
  }
}

// ---------------- attention MLP -> att_score ----------------
__global__ __launch_bounds__(256) void k_mlp(
    const float* __restrict__ W1, const float* __restrict__ b1,
    const float* __restrict__ W2, const float* __restrict__ b2,
    float* __restrict__ ws) {
  __shared__ float comb8[8][600];
  __shared__ float acc8[8];
  int b = blockIdx.x, t = threadIdx.x;
  int n0 = b*8;
  for (int i = t; i < 8*600; i += 256)
    comb8[i/600][i%600] = ws[OFF_COMB + (size_t)(n0 + i/600)*600 + (i%600)];
  if (t < 8) acc8[t] = 0.f;
  __syncthreads();
  float psum[8];
#pragma unroll
  for (int nn2 = 0; nn2 < 8; ++nn2) psum[nn2] = 0.f;
  for (int j = t; j < 300; j += 256) {
    float hh[8];
#pragma unroll
    for (int nn2 = 0; nn2 < 8; ++nn2) hh[nn2] = b1[j];
    for (int i = 0; i < 600; ++i) {
      float w = W1[(size_t)i*300 + j];
#pragma unroll
      for (int nn2 = 0; nn2 < 8; ++nn2) hh[nn2] += comb8[nn2][i]*w;
    }
    float w2 = W2[j];
#pragma unroll
    for (int nn2 = 0; nn2 < 8; ++nn2) psum[nn2] += fmaxf(hh[nn2], 0.f)*w2;
  }
#pragma unroll
  for (int nn2 = 0; nn2 < 8; ++nn2) atomicAdd(&acc8[nn2], psum[nn2]);
  __syncthreads();
  if (t < 8) {
    float v = acc8[t] + b2[0];
    ws[OFF_ATTS + n0 + t] = 1.f / (1.f + __expf(-v));
  }
}

// ---------------- per-mention scoring: raw -> z -> softmax -> s, keep -------
__device__ __forceinline__ float bsum512(float v, float* red) {
  int t = threadIdx.x;
#pragma unroll
  for (int o = 32; o; o >>= 1) v += __shfl_down(v, o);
  __syncthreads();
  if ((t & 63) == 0) red[t>>6] = v;
  __syncthreads();
  float s = 0.f;
#pragma unroll
  for (int i = 0; i < 8; ++i) s += red[i];
  return s;
}
__device__ __forceinline__ float bmax512(float v, float* red) {
  int t = threadIdx.x;
#pragma unroll
  for (int o = 32; o; o >>= 1) v = fmaxf(v, __shfl_down(v, o));
  __syncthreads();
  if ((t & 63) == 0) red[t>>6] = v;
  __syncthreads();
  float s = -INFINITY;
#pragma unroll
  for (int i = 0; i < 8; ++i) s = fmaxf(s, red[i]);
  return s;
}

__global__ __launch_bounds__(512) void k_score(
    const float* __restrict__ hand, const float* __restrict__ m2c,
    const float* __restrict__ llW, const float* __restrict__ llb,
    const float* __restrict__ me, float* __restrict__ ws) {
  __shared__ float red[8];
  __shared__ float rv[512];
  __shared__ int ri[512];
  int m = blockIdx.x, t = threadIdx.x;
  float mask = me[(size_t)m*NN + t];
  float raw = llW[0]*hand[t] + llW[1]*m2c[t] + llW[2]*ws[OFF_LOCATT + (size_t)m*NN + t]
            + llW[3]*ws[OFF_ATTS + t] + llW[4]*ws[OFF_COSST + (size_t)m*NN + t]
            + llW[5]*ws[OFF_COSDT + t] + llW[6]*ws[OFF_COSCT + (size_t)m*NN + t] + llb[0];
  float cnt = bsum512(mask, red);
  float mean = bsum512(raw*mask, red) / cnt;
  float dv = raw - mean;
  float var = bsum512(dv*dv*mask, red) / (cnt - 1.f);
  float z = dv / sqrtf(var);
  float zm = (mask > 0.f) ? z : -INFINITY;
  float mx = bmax512(zm, red);
  float e = (mask > 0.f) ? __expf(zm - mx) : 0.f;
  float ssum = bsum512(e, red);
  float sm = e / ssum * mask;
  atomicAdd(&ws[OFF_S + t], sm);
  // top-3 (ordering of sm == ordering of zm), lowest-index tie-break
  bool excl = false;
  for (int r = 0; r < 3; ++r) {
    rv[t] = excl ? -INFINITY : zm;
    ri[t] = t;
    __syncthreads();
    for (int off = 256; off; off >>= 1) {
      if (t < off) {
        float bb = rv[t+off]; int ib = ri[t+off];
        if (bb > rv[t] || (bb == rv[t] && ib < ri[t])) { rv[t] = bb; ri[t] = ib; }
      }
      __syncthreads();
    }
    int widx = ri[0];
    __syncthreads();
    if (t == 0) ws[OFF_KEEP + widx] = 1.f;
    if (t == widx) excl = true;
  }
}

// ---------------- SR row sums -> inv, init fai = s ----------------
__global__ __launch_bounds__(512) void k_grs(
    const float* __restrict__ esr, const float* __restrict__ eee,
    float* __restrict__ ws) {
  __shared__ float keep_l[NN];
  int b = blockIdx.x, t = threadIdx.x;
  keep_l[t] = ws[OFF_KEEP + t];
  __syncthreads();
  int lane = t & 63, w = t >> 6;
  int r = b*8 + w;
  float p = 0.f;
  for (int j = lane; j < NN; j += 64)
    p += esr[(size_t)r*NN + j] * eee[(size_t)r*NN + j] * keep_l[j];
#pragma unroll
  for (int o = 32; o; o >>= 1) p += __shfl_down(p, o);
  if (lane == 0) {
    ws[OFF_INV + r] = (fabsf(p) < 1e-6f) ? 1.f : 1.f/p;
    ws[OFF_FAI_A + r] = ws[OFF_S + r];
  }
}

// ---------------- one power-iteration step (guarded by it<K) ----------------
__global__ __launch_bounds__(512) void k_giter(
    const float* __restrict__ esr, const float* __restrict__ eee,
    const float* __restrict__ lamda, const int* __restrict__ rk,
    const float* __restrict__ fin, float* __restrict__ fout,
    const float* __restrict__ wsro, int it) {
  int b = blockIdx.x, t = threadIdx.x;
  int K = rk[0];
  if (it >= K) {
    if (t < 8) fout[b*8 + t] = fin[b*8 + t];
    return;
  }
  __shared__ float g[NN];
  __shared__ float red[8][65];
  g[t] = fin[t] * wsro[OFF_INV + t];
  __syncthreads();
  float lam = lamda[0];
  int jl = t & 7, ig = t >> 3;
  int j = b*8 + jl;
  float p = 0.f;
  for (int i = ig; i < NN; i += 64)
    p += g[i] * esr[(size_t)i*NN + j] * eee[(size_t)i*NN + j];
  red[jl][ig] = p;
  __syncthreads();
  if (t < 8) {
    float acc = 0.f;
    for (int i = 0; i < 64; ++i) acc += red[t][i];
    int jj = b*8 + t;
    fout[jj] = (1.f - lam) * wsro[OFF_KEEP + jj] * acc + lam * wsro[OFF_S + jj];
  }
}

// ---------------- final outputs ----------------
__global__ __launch_bounds__(512) void k_gout(
    const float* __restrict__ me, const float* __restrict__ ws, float* __restrict__ out) {
  int m = blockIdx.x, t = threadIdx.x;
  float fai = ws[OFF_FAI_A + t];
  if (m == 0) { out[t] = ws[OFF_S + t]; out[NN + t] = fai; }
  out[2*NN + (size_t)m*NN + t] = me[(size_t)m*NN + t] * fai;
}

extern "C" void kernel_launch(void* const* d_in, const int* in_sizes, int n_in,
                              void* d_out, int out_size, void* d_ws, size_t ws_size,
                              hipStream_t stream) {
  const float* embed   = (const float*)d_in[0];
  const float* W_ms    = (const float*)d_in[1];
  const float* b_ms    = (const float*)d_in[2];
  const float* W_mc    = (const float*)d_in[3];
  const float* b_mc    = (const float*)d_in[4];
  const float* att_W1  = (const float*)d_in[5];
  const float* att_b1  = (const float*)d_in[6];
  const float* att_W2  = (const float*)d_in[7];
  const float* att_b2  = (const float*)d_in[8];
  const float* ll_W    = (const float*)d_in[9];
  const float* ll_b    = (const float*)d_in[10];
  const float* lamda   = (const float*)d_in[11];
  const int* mention_ids = (const int*)d_in[12];
  const int* context_ids = (const int*)d_in[13];
  const int* doc_ids     = (const int*)d_in[14];
  const int* body_ids    = (const int*)d_in[15];
  const int* cand_ids    = (const int*)d_in[16];
  const float* title   = (const float*)d_in[17];
  const float* bert    = (const float*)d_in[18];
  const float* hand    = (const float*)d_in[19];
  const float* m2c     = (const float*)d_in[20];
  const float* me      = (const float*)d_in[21];
  const float* eee     = (const float*)d_in[22];
  const float* esr     = (const float*)d_in[23];
  const int* rk        = (const int*)d_in[24];
  float* ws  = (float*)d_ws;
  float* out = (float*)d_out;

  hipLaunchKernelGGL(k_init, dim3(NN), dim3(64), 0, stream, embed, title, bert, cand_ids, doc_ids, ws);
  hipLaunchKernelGGL(k_gather, dim3(MM), dim3(256), 0, stream, embed, context_ids, ws);
  hipLaunchKernelGGL(k_wt, dim3(1500), dim3(256), 0, stream, W_mc, ws);
  hipLaunchKernelGGL(k_ms, dim3(MM), dim3(256), 0, stream, embed, mention_ids, W_ms, b_ms, ws);
  hipLaunchKernelGGL(k_mc_gemm, dim3(MM, 6), dim3(256), 0, stream, b_mc, ws);
  hipLaunchKernelGGL(k_cos, dim3(MM), dim3(256), 0, stream, title, ws);
  hipLaunchKernelGGL(k_att, dim3(NN, NHEAD), dim3(256), 0, stream, embed, body_ids, ws);
  hipLaunchKernelGGL(k_local, dim3(MM, 4), dim3(256), 0, stream, ws);
  hipLaunchKernelGGL(k_mlp, dim3(64), dim3(256), 0, stream, att_W1, att_b1, att_W2, att_b2, ws);
  hipLaunchKernelGGL(k_score, dim3(MM), dim3(512), 0, stream, hand, m2c, ll_W, ll_b, me, ws);
  hipLaunchKernelGGL(k_grs, dim3(64), dim3(512), 0, stream, esr, eee, ws);
  float* fa = ws + OFF_FAI_A;
  float* fb = ws + OFF_FAI_B;
  for (int it = 0; it < 8; ++it) {
    hipLaunchKernelGGL(k_giter, dim3(64), dim3(512), 0, stream, esr, eee, lamda, rk,
                       (it & 1) ? fb : fa, (it & 1) ? fa : fb, ws, it);
  }
  hipLaunchKernelGGL(k_gout, dim3(MM), dim3(512), 0, stream, me, ws, out);
}

// Round 3
// 1054.032 us; speedup vs baseline: 4.5306x; 1.5574x over previous
//
#include <hip/hip_runtime.h>
#include <math.h>

#define MM 64
#define NN 512
#define DD 300
#define FF 768
#define CTXL 50
#define DOCL 100
#define BODYL 200
#define NHEAD 5
#define HD 60

typedef __attribute__((ext_vector_type(8))) short bf16x8;
typedef __attribute__((ext_vector_type(4))) float f32x4;
#define MFMA16(A,B,C) __builtin_amdgcn_mfma_f32_16x16x32_bf16(A,B,C,0,0,0)

__device__ __forceinline__ ushort f2bf(float f) {
  uint u = __float_as_uint(f);
  uint r = (u + 0x7FFFu + ((u >> 16) & 1u)) >> 16;   // RNE
  return (ushort)r;
}
__device__ __forceinline__ float bf2f(ushort h) {
  return __uint_as_float(((uint)h) << 16);
}

// ---------------- workspace layout (float offsets) ----------------
static constexpr size_t OFF_MS    = 0;                    // 64*768
static constexpr size_t OFF_MC    = 49152;                // 64*768
static constexpr size_t OFF_TNORM = 98304;                // 512
static constexpr size_t OFF_COSDT = 98816;                // 512
static constexpr size_t OFF_CAND  = 99328;                // 512*300
static constexpr size_t OFF_DOC   = 252928;               // 100*300
static constexpr size_t OFF_COMB  = 282928;               // 512*600
static constexpr size_t OFF_ATTS  = 590128;               // 512
static constexpr size_t OFF_COSST = 590640;               // 64*512
static constexpr size_t OFF_COSCT = 623408;               // 64*512
static constexpr size_t OFF_LOCATT= 656176;               // 64*512
static constexpr size_t OFF_S     = 688944;               // 512
static constexpr size_t OFF_KEEP  = 689456;               // 512
static constexpr size_t OFF_INV   = 689968;               // 512
static constexpr size_t OFF_FAI_A = 690480;               // 512
static constexpr size_t OFF_FAI_B = 690992;               // 512
static constexpr size_t OFF_CTXG  = 691504;               // 64*52*300 (2 pad rows/mention)
static constexpr size_t OFF_WT    = 1689904;              // 1500*768 transposed W_mc
// total 2841904 floats = 11.4 MB

// ---------------- init: title norms, cos_dt, cand/doc gathers, zero s/keep ----
__global__ __launch_bounds__(64) void k_init(
    const float* __restrict__ embed, const float* __restrict__ title,
    const float* __restrict__ bert, const int* __restrict__ cand_ids,
    const int* __restrict__ doc_ids, float* __restrict__ ws) {
  int n = blockIdx.x, t = threadIdx.x;
  float ss = 0.f, dd = 0.f, bb = 0.f;
  for (int j = t; j < FF; j += 64) {
    float tv = title[(size_t)n*FF + j], bv = bert[j];
    ss += tv*tv; dd += tv*bv; bb += bv*bv;
  }
#pragma unroll
  for (int o = 32; o; o >>= 1) {
    ss += __shfl_down(ss, o); dd += __shfl_down(dd, o); bb += __shfl_down(bb, o);
  }
  if (t == 0) {
    float tn = fmaxf(sqrtf(ss), 1e-6f);
    float bn = fmaxf(sqrtf(bb), 1e-6f);
    ws[OFF_TNORM + n] = tn;
    ws[OFF_COSDT + n] = dd / (tn * bn);
  }
  size_t cid = (size_t)cand_ids[n] * DD;
  for (int j = t; j < DD; j += 64) ws[OFF_CAND + (size_t)n*DD + j] = embed[cid + j];
  if (n < DOCL) {
    size_t did = (size_t)doc_ids[n] * DD;
    for (int j = t; j < DD; j += 64) ws[OFF_DOC + (size_t)n*DD + j] = embed[did + j];
  }
  if (n == 0) {
    for (int j = t; j < NN; j += 64) { ws[OFF_S + j] = 0.f; ws[OFF_KEEP + j] = 0.f; }
  }
}

// ---------------- gather ctx embeddings once ----------------
__global__ __launch_bounds__(256) void k_gather(
    const float* __restrict__ embed, const int* __restrict__ context_ids,
    float* __restrict__ ws) {
  int m = blockIdx.x, t = threadIdx.x;
  float* dst = ws + OFF_CTXG + (size_t)m*52*DD;
  for (int i = t; i < 52*DD; i += 256) {
    int r = i / DD, c = i - r*DD;
    dst[i] = (r < CTXL) ? embed[(size_t)context_ids[m*CTXL + r]*DD + c] : 0.f;
  }
}

// ---------------- transpose W_mc [f][d][k] -> Wt[k*300+d][f] ----------------
__global__ __launch_bounds__(256) void k_wt(
    const float* __restrict__ W, float* __restrict__ ws) {
  int kd = blockIdx.x;
  int k = kd / DD, d = kd - k*DD;
  int t = threadIdx.x;
  float* dst = ws + OFF_WT + (size_t)kd*FF;
  for (int f = t; f < FF; f += 256) dst[f] = W[(size_t)f*(DD*5) + d*5 + k];
}

// ---------------- mention surface conv (k=2, L=4 -> 3), relu, mean ----------
__global__ __launch_bounds__(256) void k_ms(
    const float* __restrict__ embed, const int* __restrict__ mention_ids,
    const float* __restrict__ W, const float* __restrict__ b, float* __restrict__ ws) {
  __shared__ float x[4][DD];
  int m = blockIdx.x, t = threadIdx.x;
  for (int i = t; i < 4*DD; i += 256) {
    int r = i / DD, c = i % DD;
    x[r][c] = embed[(size_t)mention_ids[m*4 + r]*DD + c];
  }
  __syncthreads();
  for (int f = t; f < FF; f += 256) {
    const float* w = W + (size_t)f * (DD*2);
    float bb = b[f];
    float acc = 0.f;
#pragma unroll
    for (int tt = 0; tt < 3; ++tt) {
      float y = bb;
      for (int d = 0; d < DD; ++d) {
        float2 wv = *(const float2*)&w[d*2];
        y += wv.x * x[tt][d] + wv.y * x[tt+1][d];
      }
      acc += fmaxf(y, 0.f);
    }
    ws[OFF_MS + (size_t)m*FF + f] = acc * (1.f/3.f);
  }
}

// ---------------- context conv as tiled GEMM --------------------------------
__global__ __launch_bounds__(256) void k_mc_gemm(
    const float* __restrict__ b_mc, float* __restrict__ ws) {
  __shared__ float As[50][49];
  __shared__ float Bs[50][128];
  int m = blockIdx.x, f0 = blockIdx.y * 128, t = threadIdx.x;
  int tr = t >> 4, tc = t & 15;
  const float* ctxm = ws + OFF_CTXG + (size_t)m*52*DD;
  const float4* wt4 = (const float4*)(ws + OFF_WT);
  float acc[3][8];
#pragma unroll
  for (int r = 0; r < 3; ++r)
#pragma unroll
    for (int j = 0; j < 8; ++j) acc[r][j] = 0.f;

  for (int chunk = 0; chunk < 30; ++chunk) {
    int k = chunk / 6, dc = (chunk - k*6) * 50;
    for (int i = t; i < 48*50; i += 256) {
      int row = i / 50, kj = i - row*50;
      As[kj][row] = ctxm[(row + k)*DD + dc + kj];
    }
    for (int i = t; i < 1600; i += 256) {
      int kj = i >> 5, fq = i & 31;
      *(float4*)&Bs[kj][fq*4] = wt4[((size_t)(k*DD + dc + kj)*FF + f0 + fq*4) >> 2];
    }
    __syncthreads();
#pragma unroll 2
    for (int kj = 0; kj < 50; ++kj) {
      float a0 = As[kj][tr], a1 = As[kj][tr+16], a2 = As[kj][tr+32];
      float4 b0 = *(const float4*)&Bs[kj][tc*8];
      float4 b1 = *(const float4*)&Bs[kj][tc*8+4];
      float bb[8] = {b0.x,b0.y,b0.z,b0.w,b1.x,b1.y,b1.z,b1.w};
#pragma unroll
      for (int j = 0; j < 8; ++j) {
        acc[0][j] += a0*bb[j]; acc[1][j] += a1*bb[j]; acc[2][j] += a2*bb[j];
      }
    }
    __syncthreads();
  }
  float bv[8], p[8];
#pragma unroll
  for (int j = 0; j < 8; ++j) { bv[j] = b_mc[f0 + tc*8 + j]; p[j] = 0.f; }
#pragma unroll
  for (int rr = 0; rr < 3; ++rr) {
    int row = tr + 16*rr;
    if (row < 46) {
#pragma unroll
      for (int j = 0; j < 8; ++j) p[j] += fmaxf(acc[rr][j] + bv[j], 0.f);
    }
  }
  float* red = &Bs[0][0];
#pragma unroll
  for (int j = 0; j < 8; ++j) red[tr*128 + tc*8 + j] = p[j];
  __syncthreads();
  if (t < 128) {
    float s = 0.f;
#pragma unroll
    for (int i = 0; i < 16; ++i) s += red[i*128 + t];
    ws[OFF_MC + (size_t)m*FF + f0 + t] = s * (1.f/46.f);
  }
}

// ---------------- cos_st / cos_ct ----------------
__global__ __launch_bounds__(256) void k_cos(
    const float* __restrict__ title, float* __restrict__ ws) {
  __shared__ float a[FF], bv_[FF];
  __shared__ float redA[4], redB[4];
  int m = blockIdx.x, t = threadIdx.x;
  float pa = 0.f, pb = 0.f;
  for (int j = t; j < FF; j += 256) {
    float v = ws[OFF_MS + (size_t)m*FF + j]; a[j] = v; pa += v*v;
    float u = ws[OFF_MC + (size_t)m*FF + j]; bv_[j] = u; pb += u*u;
  }
#pragma unroll
  for (int o = 32; o; o >>= 1) { pa += __shfl_down(pa, o); pb += __shfl_down(pb, o); }
  if ((t & 63) == 0) { redA[t>>6] = pa; redB[t>>6] = pb; }
  __syncthreads();
  float na = fmaxf(sqrtf(redA[0]+redA[1]+redA[2]+redA[3]), 1e-6f);
  float nb = fmaxf(sqrtf(redB[0]+redB[1]+redB[2]+redB[3]), 1e-6f);
  float ia = 1.f / na, ib = 1.f / nb;
  for (int n = t; n < NN; n += 256) {
    const float4* tr = (const float4*)(title + (size_t)n*FF);
    float ds = 0.f, dc = 0.f;
    for (int j = 0; j < FF/4; ++j) {
      float4 tv = tr[j];
      float4 av = *(const float4*)&a[j*4];
      float4 bw = *(const float4*)&bv_[j*4];
      ds += av.x*tv.x + av.y*tv.y + av.z*tv.z + av.w*tv.w;
      dc += bw.x*tv.x + bw.y*tv.y + bw.z*tv.z + bw.w*tv.w;
    }
    float it = 1.f / ws[OFF_TNORM + n];
    ws[OFF_COSST + (size_t)m*NN + n] = ds * ia * it;
    ws[OFF_COSCT + (size_t)m*NN + n] = dc * ib * it;
  }
}

// ============ 5-head doc<->body attention via MFMA + expm1 trick ============
// Per block (n,h). E = exp(S*scale) = 1 + x. att_db numerator = colsum_kh + X*kh,
// rs = 200 + rowsum(X). att_bd numerator = colsum_qh + X^T*qh, cs = 100 + colsum(X).
// All GEMMs bf16 MFMA 16x16x32, k chunked by 32 (7 chunks cover 224 >= 200).
__global__ __launch_bounds__(256) void k_att(
    const float* __restrict__ embed, const int* __restrict__ body_ids,
    float* __restrict__ ws) {
  // bf16 LDS, 16B-slot XOR swizzle where rows would alias banks
  __shared__ __align__(16) ushort qhB[112*64];   // [q][j]  swz slot^ (q&7)
  __shared__ __align__(16) ushort qhT[64*128];   // [d][q]  swz slot^ (d&7)
  __shared__ __align__(16) ushort khBc[32*64];   // [kk][j] swz slot^ (kk&7), per chunk
  __shared__ __align__(16) ushort khTc[64*48];   // [d][kk] linear, per chunk
  __shared__ __align__(16) ushort XA[112*48];    // [q][kk] linear, per chunk
  __shared__ __align__(16) ushort XT[32*128];    // [kk][q] swz slot^(kk&7), per chunk
  __shared__ float rs_acc[112];
  __shared__ float cs_c[32];
  __shared__ float csqL[64];
  __shared__ float cskL[64];

  const float SCALE = 0.1290994448735806f; // 1/sqrt(60)
  int n = blockIdx.x, h = blockIdx.y, t = threadIdx.x;
  int w = t >> 6, l = t & 63;
  int l15 = l & 15, l4 = l >> 4;
  const float* doc = ws + OFF_DOC;

  // ---- inits ----
  if (t < 112) rs_acc[t] = 0.f;
  else if (t < 176) cskL[t-112] = 0.f;
  // zero XT logical q-slots 14,15 (q 112..127, never written)
  if (t < 64) {
    int kk = t >> 1, ls = 14 + (t & 1);
    int ps = ls ^ (kk & 7);
    uint4 z = {0,0,0,0};
    *(uint4*)&XT[kk*128 + ps*8] = z;
  }

  // ---- S0: stage qhB ----
  for (int u = t; u < 112*8; u += 256) {
    int q = u >> 3, j8 = u & 7;
    uint pk[4] = {0,0,0,0};
    if (q < 100) {
      const float* src = doc + q*DD + h*HD;
#pragma unroll
      for (int i = 0; i < 8; ++i) {
        int j = j8*8 + i;
        float v = (j < HD) ? src[j] : 0.f;
        pk[i>>1] |= ((uint)f2bf(v)) << ((i & 1) * 16);
      }
    }
    int slot = j8 ^ (q & 7);
    *(uint4*)&qhB[q*64 + slot*8] = make_uint4(pk[0], pk[1], pk[2], pk[3]);
  }
  // ---- S0: stage qhT ----
  for (int u = t; u < 64*16; u += 256) {
    int d = u >> 4, q8 = u & 15;
    uint pk[4] = {0,0,0,0};
    if (d < HD) {
#pragma unroll
      for (int i = 0; i < 8; ++i) {
        int q = q8*8 + i;
        float v = (q < 100) ? doc[q*DD + h*HD + d] : 0.f;
        pk[i>>1] |= ((uint)f2bf(v)) << ((i & 1) * 16);
      }
    }
    int slot = q8 ^ (d & 7);
    *(uint4*)&qhT[d*128 + slot*8] = make_uint4(pk[0], pk[1], pk[2], pk[3]);
  }
  __syncthreads();
  // csq[d] from qhT (bf16 source; constant shift across n -> cancels in z-score)
  if (t < 64) {
    int d = t;
    float s = 0.f;
    for (int ls = 0; ls < 13; ++ls) {       // logical q-slots 0..12 cover q<104
      int ps = ls ^ (d & 7);
      const ushort* p = &qhT[d*128 + ps*8];
#pragma unroll
      for (int i = 0; i < 8; ++i) {
        int q = ls*8 + i;
        if (q < 100) s += bf2f(p[i]);
      }
    }
    csqL[t] = s;
  }
  __syncthreads();
  float csq_r = csqL[16*w + l15];

  // persistent accumulators
  f32x4 Cdb[7];
#pragma unroll
  for (int i = 0; i < 7; ++i) Cdb[i] = (f32x4){0.f,0.f,0.f,0.f};
  float bdmx = -1e30f;

  const int* bids = body_ids + n*BODYL;

  for (int c = 0; c < 7; ++c) {
    int k0 = c * 32;
    // ---- P0: stage khBc (one unit per thread) ----
    {
      int kk = t >> 3, j8 = t & 7;
      int kg = k0 + kk;
      uint pk[4] = {0,0,0,0};
      if (kg < BODYL) {
        const float* src = embed + (size_t)bids[kg]*DD + h*HD;
#pragma unroll
        for (int i = 0; i < 8; ++i) {
          int j = j8*8 + i;
          float v = (j < HD) ? src[j] : 0.f;
          pk[i>>1] |= ((uint)f2bf(v)) << ((i & 1) * 16);
        }
      }
      int slot = j8 ^ (kk & 7);
      *(uint4*)&khBc[kk*64 + slot*8] = make_uint4(pk[0], pk[1], pk[2], pk[3]);
    }
    // ---- P0: stage khTc ----
    {
      int d = t >> 2, kk8 = t & 3;
      uint pk[4] = {0,0,0,0};
      if (d < HD) {
#pragma unroll
        for (int i = 0; i < 8; ++i) {
          int kg = k0 + kk8*8 + i;
          float v = (kg < BODYL) ? embed[(size_t)bids[kg]*DD + h*HD + d] : 0.f;
          pk[i>>1] |= ((uint)f2bf(v)) << ((i & 1) * 16);
        }
      }
      *(uint4*)&khTc[d*48 + kk8*8] = make_uint4(pk[0], pk[1], pk[2], pk[3]);
    }
    __syncthreads();

    // ---- P1: GEMM1  S^T[k][q] = kh . qh^T  -> x -> XA, XT ----
    for (int task = w; task < 14; task += 4) {
      int mt = task / 7, nt = task - mt*7;
      int krow = 16*mt + l15;
      int qrow = 16*nt + l15;
      f32x4 acc = {0.f,0.f,0.f,0.f};
#pragma unroll
      for (int js = 0; js < 2; ++js) {
        bf16x8 a = *(const bf16x8*)&khBc[krow*64 + ((js*4 + l4) ^ (krow & 7))*8];
        bf16x8 b = *(const bf16x8*)&qhB[qrow*64 + ((js*4 + l4) ^ (qrow & 7))*8];
        acc = MFMA16(a, b, acc);
      }
      // D: col(q) = l&15 within nt; rows(k) = 16mt + 4*l4 + r
      int q = qrow;
      int kkb = 16*mt + 4*l4;
      ushort xs[4];
#pragma unroll
      for (int r = 0; r < 4; ++r) {
        int kg = k0 + kkb + r;
        float x = (q < 100 && kg < BODYL) ? (__expf(acc[r]*SCALE) - 1.f) : 0.f;
        xs[r] = f2bf(x);
      }
      // XA[q][kkb..kkb+3] one 8B write
      uint2 wv = make_uint2((uint)xs[0] | ((uint)xs[1] << 16),
                            (uint)xs[2] | ((uint)xs[3] << 16));
      *(uint2*)&XA[q*48 + kkb] = wv;
      // XT scalar writes (swizzled)
#pragma unroll
      for (int r = 0; r < 4; ++r) {
        int kk = kkb + r;
        XT[kk*128 + (((q >> 3) ^ (kk & 7))*8) + (q & 7)] = xs[r];
      }
    }
    __syncthreads();

    // ---- P3: mini reductions ----
    if (t < 112) {                     // rs += rowsum(XA[t][0:32])
      float s = 0.f;
      const uint4* p = (const uint4*)&XA[t*48];
#pragma unroll
      for (int b4 = 0; b4 < 4; ++b4) {
        uint4 v = p[b4];
        uint vv[4] = {v.x, v.y, v.z, v.w};
#pragma unroll
        for (int i = 0; i < 4; ++i) {
          s += bf2f((ushort)(vv[i] & 0xFFFF)) + bf2f((ushort)(vv[i] >> 16));
        }
      }
      rs_acc[t] += s;
    } else if (t < 144) {              // cs_c[kk] = 100 + colsum over q<112
      int kk = t - 112;
      float s = 0.f;
      for (int ls = 0; ls < 14; ++ls) {
        int ps = ls ^ (kk & 7);
        const uint4* p = (const uint4*)&XT[kk*128 + ps*8];
        uint4 v = *p;
        uint vv[4] = {v.x, v.y, v.z, v.w};
#pragma unroll
        for (int i = 0; i < 4; ++i) {
          s += bf2f((ushort)(vv[i] & 0xFFFF)) + bf2f((ushort)(vv[i] >> 16));
        }
      }
      cs_c[kk] = 100.f + s;
    } else if (t < 208) {              // csk += rowsum(khTc[d][0:32])
      int d = t - 144;
      float s = 0.f;
      const uint4* p = (const uint4*)&khTc[d*48];
#pragma unroll
      for (int b4 = 0; b4 < 4; ++b4) {
        uint4 v = p[b4];
        uint vv[4] = {v.x, v.y, v.z, v.w};
#pragma unroll
        for (int i = 0; i < 4; ++i) {
          s += bf2f((ushort)(vv[i] & 0xFFFF)) + bf2f((ushort)(vv[i] >> 16));
        }
      }
      cskL[d] += s;
    }
    __syncthreads();

    // ---- P4: GEMM2 partial  Cdb[q][d] += XA . khTc ---- (wave w owns d-tile w)
    {
      int d = 16*w + l15;
      bf16x8 bfr = *(const bf16x8*)&khTc[d*48 + l4*8];
#pragma unroll
      for (int mt2 = 0; mt2 < 7; ++mt2) {
        int q = 16*mt2 + l15;
        bf16x8 afr = *(const bf16x8*)&XA[q*48 + l4*8];
        Cdb[mt2] = MFMA16(afr, bfr, Cdb[mt2]);
      }
    }
    // ---- P5: GEMM3  Cbd[k][d] = XT . qhT, finalize this chunk's att_bd ----
    {
      int d = 16*w + l15;
#pragma unroll
      for (int kt = 0; kt < 2; ++kt) {
        int kk = 16*kt + l15;
        f32x4 acc3 = {0.f,0.f,0.f,0.f};
#pragma unroll
        for (int qs = 0; qs < 4; ++qs) {
          bf16x8 afr = *(const bf16x8*)&XT[kk*128 + ((qs*4 + l4) ^ (kk & 7))*8];
          bf16x8 bfr = *(const bf16x8*)&qhT[d*128 + ((qs*4 + l4) ^ (d & 7))*8];
          acc3 = MFMA16(afr, bfr, acc3);
        }
#pragma unroll
        for (int r = 0; r < 4; ++r) {
          int kkr = 16*kt + 4*l4 + r;
          int kg = k0 + kkr;
          if (kg < BODYL) {
            float v = (csq_r + acc3[r]) / cs_c[kkr];
            bdmx = fmaxf(bdmx, v);
          }
        }
      }
    }
    __syncthreads();
  }

  // ---- finalize att_db ----
  float csk_r = cskL[16*w + l15];
  float dbmx = -1e30f;
#pragma unroll
  for (int mt2 = 0; mt2 < 7; ++mt2) {
#pragma unroll
    for (int r = 0; r < 4; ++r) {
      int q = 16*mt2 + 4*l4 + r;
      if (q < 100) {
        float v = (csk_r + Cdb[mt2][r]) / (200.f + rs_acc[q]);
        dbmx = fmaxf(dbmx, v);
      }
    }
  }
  dbmx = fmaxf(dbmx, __shfl_xor(dbmx, 16));
  dbmx = fmaxf(dbmx, __shfl_xor(dbmx, 32));
  bdmx = fmaxf(bdmx, __shfl_xor(bdmx, 16));
  bdmx = fmaxf(bdmx, __shfl_xor(bdmx, 32));
  int d = 16*w + l15;
  if (l4 == 0 && d < HD) {
    ws[OFF_COMB + (size_t)n*600 + h*HD + d] = dbmx;
    ws[OFF_COMB + (size_t)n*600 + 300 + h*HD + d] = bdmx;
  }
}

// ---------------- local context attention: max_t ctx.cand / sqrt(300) -------
__global__ __launch_bounds__(256) void k_local(
    float* __restrict__ ws) {
  __shared__ __align__(16) float x[CTXL][304];
  __shared__ float red[2][128];
  int m = blockIdx.x, nc = blockIdx.y, t = threadIdx.x;
  const float* ctxm = ws + OFF_CTXG + (size_t)m*52*DD;
  for (int i = t; i < CTXL*DD; i += 256) {
    int r = i / DD, c = i % DD;
    x[r][c] = ctxm[i];
  }
  __syncthreads();
  int nl = t & 127, half = t >> 7;
  int n = nc*128 + nl;
  const float4* cr = (const float4*)(ws + OFF_CAND + (size_t)n*DD);
  float acc[25];
#pragma unroll
  for (int i = 0; i < 25; ++i) acc[i] = 0.f;
  for (int d4 = 0; d4 < 75; ++d4) {
    float4 cv = cr[d4];
#pragma unroll
    for (int i = 0; i < 25; ++i) {
      float4 xv = *(const float4*)&x[half*25 + i][d4*4];
      acc[i] += xv.x*cv.x + xv.y*cv.y + xv.z*cv.z + xv.w*cv.w;
    }
  }
  float mx = -1e30f;
#pragma unroll
  for (int i = 0; i < 25; ++i) mx = fmaxf(mx, acc[i]);
  red[half][nl] = mx;
  __syncthreads();
  if (t < 128) {
    float v = fmaxf(red[0][t], red[1][t]) * 0.05773502691896258f;
    ws[OFF_LOCATT + (size_t)m*NN + nc*128 + t] = v;
  }
}

// ---------------- attention MLP -> att_score ----------------
__global__ __launch_bounds__(256) void k_mlp(
    const float* __restrict__ W1, const float* __restrict__ b1,
    const float* __restrict__ W2, const float* __restrict__ b2,
    float* __restrict__ ws) {
  __shared__ float comb8[8][600];
  __shared__ float acc8[8];
  int b = blockIdx.x, t = threadIdx.x;
  int n0 = b*8;
  for (int i = t; i < 8*600; i += 256)
    comb8[i/600][i%600] = ws[OFF_COMB + (size_t)(n0 + i/600)*600 + (i%600)];
  if (t < 8) acc8[t] = 0.f;
  __syncthreads();
  float psum[8];
#pragma unroll
  for (int nn2 = 0; nn2 < 8; ++nn2) psum[nn2] = 0.f;
  for (int j = t; j < 300; j += 256) {
    float hh[8];
#pragma unroll
    for (int nn2 = 0; nn2 < 8; ++nn2) hh[nn2] = b1[j];
    for (int i = 0; i < 600; ++i) {
      float w = W1[(size_t)i*300 + j];
#pragma unroll
      for (int nn2 = 0; nn2 < 8; ++nn2) hh[nn2] += comb8[nn2][i]*w;
    }
    float w2 = W2[j];
#pragma unroll
    for (int nn2 = 0; nn2 < 8; ++nn2) psum[nn2] += fmaxf(hh[nn2], 0.f)*w2;
  }
#pragma unroll
  for (int nn2 = 0; nn2 < 8; ++nn2) atomicAdd(&acc8[nn2], psum[nn2]);
  __syncthreads();
  if (t < 8) {
    float v = acc8[t] + b2[0];
    ws[OFF_ATTS + n0 + t] = 1.f / (1.f + __expf(-v));
  }
}

// ---------------- per-mention scoring ----------------
__device__ __forceinline__ float bsum512(float v, float* red) {
  int t = threadIdx.x;
#pragma unroll
  for (int o = 32; o; o >>= 1) v += __shfl_down(v, o);
  __syncthreads();
  if ((t & 63) == 0) red[t>>6] = v;
  __syncthreads();
  float s = 0.f;
#pragma unroll
  for (int i = 0; i < 8; ++i) s += red[i];
  return s;
}
__device__ __forceinline__ float bmax512(float v, float* red) {
  int t = threadIdx.x;
#pragma unroll
  for (int o = 32; o; o >>= 1) v = fmaxf(v, __shfl_down(v, o));
  __syncthreads();
  if ((t & 63) == 0) red[t>>6] = v;
  __syncthreads();
  float s = -INFINITY;
#pragma unroll
  for (int i = 0; i < 8; ++i) s = fmaxf(s, red[i]);
  return s;
}

__global__ __launch_bounds__(512) void k_score(
    const float* __restrict__ hand, const float* __restrict__ m2c,
    const float* __restrict__ llW, const float* __restrict__ llb,
    const float* __restrict__ me, float* __restrict__ ws) {
  __shared__ float red[8];
  __shared__ float rv[512];
  __shared__ int ri[512];
  int m = blockIdx.x, t = threadIdx.x;
  float mask = me[(size_t)m*NN + t];
  float raw = llW[0]*hand[t] + llW[1]*m2c[t] + llW[2]*ws[OFF_LOCATT + (size_t)m*NN + t]
            + llW[3]*ws[OFF_ATTS + t] + llW[4]*ws[OFF_COSST + (size_t)m*NN + t]
            + llW[5]*ws[OFF_COSDT + t] + llW[6]*ws[OFF_COSCT + (size_t)m*NN + t] + llb[0];
  float cnt = bsum512(mask, red);
  float mean = bsum512(raw*mask, red) / cnt;
  float dv = raw - mean;
  float var = bsum512(dv*dv*mask, red) / (cnt - 1.f);
  float z = dv / sqrtf(var);
  float zm = (mask > 0.f) ? z : -INFINITY;
  float mx = bmax512(zm, red);
  float e = (mask > 0.f) ? __expf(zm - mx) : 0.f;
  float ssum = bsum512(e, red);
  float sm = e / ssum * mask;
  atomicAdd(&ws[OFF_S + t], sm);
  bool excl = false;
  for (int r = 0; r < 3; ++r) {
    rv[t] = excl ? -INFINITY : zm;
    ri[t] = t;
    __syncthreads();
    for (int off = 256; off; off >>= 1) {
      if (t < off) {
        float bb = rv[t+off]; int ib = ri[t+off];
        if (bb > rv[t] || (bb == rv[t] && ib < ri[t])) { rv[t] = bb; ri[t] = ib; }
      }
      __syncthreads();
    }
    int widx = ri[0];
    __syncthreads();
    if (t == 0) ws[OFF_KEEP + widx] = 1.f;
    if (t == widx) excl = true;
  }
}

// ---------------- SR row sums -> inv, init fai = s ----------------
__global__ __launch_bounds__(512) void k_grs(
    const float* __restrict__ esr, const float* __restrict__ eee,
    float* __restrict__ ws) {
  __shared__ float keep_l[NN];
  int b = blockIdx.x, t = threadIdx.x;
  keep_l[t] = ws[OFF_KEEP + t];
  __syncthreads();
  int lane = t & 63, w = t >> 6;
  int r = b*8 + w;
  float p = 0.f;
  for (int j = lane; j < NN; j += 64)
    p += esr[(size_t)r*NN + j] * eee[(size_t)r*NN + j] * keep_l[j];
#pragma unroll
  for (int o = 32; o; o >>= 1) p += __shfl_down(p, o);
  if (lane == 0) {
    ws[OFF_INV + r] = (fabsf(p) < 1e-6f) ? 1.f : 1.f/p;
    ws[OFF_FAI_A + r] = ws[OFF_S + r];
  }
}

// ---------------- one power-iteration step ----------------
__global__ __launch_bounds__(512) void k_giter(
    const float* __restrict__ esr, const float* __restrict__ eee,
    const float* __restrict__ lamda, const int* __restrict__ rk,
    const float* __restrict__ fin, float* __restrict__ fout,
    const float* __restrict__ wsro, int it) {
  int b = blockIdx.x, t = threadIdx.x;
  int K = rk[0];
  if (it >= K) {
    if (t < 8) fout[b*8 + t] = fin[b*8 + t];
    return;
  }
  __shared__ float g[NN];
  __shared__ float red[8][65];
  g[t] = fin[t] * wsro[OFF_INV + t];
  __syncthreads();
  float lam = lamda[0];
  int jl = t & 7, ig = t >> 3;
  int j = b*8 + jl;
  float p = 0.f;
  for (int i = ig; i < NN; i += 64)
    p += g[i] * esr[(size_t)i*NN + j] * eee[(size_t)i*NN + j];
  red[jl][ig] = p;
  __syncthreads();
  if (t < 8) {
    float acc = 0.f;
    for (int i = 0; i < 64; ++i) acc += red[t][i];
    int jj = b*8 + t;
    fout[jj] = (1.f - lam) * wsro[OFF_KEEP + jj] * acc + lam * wsro[OFF_S + jj];
  }
}

// ---------------- final outputs ----------------
__global__ __launch_bounds__(512) void k_gout(
    const float* __restrict__ me, const float* __restrict__ ws, float* __restrict__ out) {
  int m = blockIdx.x, t = threadIdx.x;
  float fai = ws[OFF_FAI_A + t];
  if (m == 0) { out[t] = ws[OFF_S + t]; out[NN + t] = fai; }
  out[2*NN + (size_t)m*NN + t] = me[(size_t)m*NN + t] * fai;
}

extern "C" void kernel_launch(void* const* d_in, const int* in_sizes, int n_in,
                              void* d_out, int out_size, void* d_ws, size_t ws_size,
                              hipStream_t stream) {
  const float* embed   = (const float*)d_in[0];
  const float* W_ms    = (const float*)d_in[1];
  const float* b_ms    = (const float*)d_in[2];
  const float* W_mc    = (const float*)d_in[3];
  const float* b_mc    = (const float*)d_in[4];
  const float* att_W1  = (const float*)d_in[5];
  const float* att_b1  = (const float*)d_in[6];
  const float* att_W2  = (const float*)d_in[7];
  const float* att_b2  = (const float*)d_in[8];
  const float* ll_W    = (const float*)d_in[9];
  const float* ll_b    = (const float*)d_in[10];
  const float* lamda   = (const float*)d_in[11];
  const int* mention_ids = (const int*)d_in[12];
  const int* context_ids = (const int*)d_in[13];
  const int* doc_ids     = (const int*)d_in[14];
  const int* body_ids    = (const int*)d_in[15];
  const int* cand_ids    = (const int*)d_in[16];
  const float* title   = (const float*)d_in[17];
  const float* bert    = (const float*)d_in[18];
  const float* hand    = (const float*)d_in[19];
  const float* m2c     = (const float*)d_in[20];
  const float* me      = (const float*)d_in[21];
  const float* eee     = (const float*)d_in[22];
  const float* esr     = (const float*)d_in[23];
  const int* rk        = (const int*)d_in[24];
  float* ws  = (float*)d_ws;
  float* out = (float*)d_out;

  hipLaunchKernelGGL(k_init, dim3(NN), dim3(64), 0, stream, embed, title, bert, cand_ids, doc_ids, ws);
  hipLaunchKernelGGL(k_gather, dim3(MM), dim3(256), 0, stream, embed, context_ids, ws);
  hipLaunchKernelGGL(k_wt, dim3(1500), dim3(256), 0, stream, W_mc, ws);
  hipLaunchKernelGGL(k_ms, dim3(MM), dim3(256), 0, stream, embed, mention_ids, W_ms, b_ms, ws);
  hipLaunchKernelGGL(k_mc_gemm, dim3(MM, 6), dim3(256), 0, stream, b_mc, ws);
  hipLaunchKernelGGL(k_cos, dim3(MM), dim3(256), 0, stream, title, ws);
  hipLaunchKernelGGL(k_att, dim3(NN, NHEAD), dim3(256), 0, stream, embed, body_ids, ws);
  hipLaunchKernelGGL(k_local, dim3(MM, 4), dim3(256), 0, stream, ws);
  hipLaunchKernelGGL(k_mlp, dim3(64), dim3(256), 0, stream, att_W1, att_b1, att_W2, att_b2, ws);
  hipLaunchKernelGGL(k_score, dim3(MM), dim3(512), 0, stream, hand, m2c, ll_W, ll_b, me, ws);
  hipLaunchKernelGGL(k_grs, dim3(64), dim3(512), 0, stream, esr, eee, ws);
  float* fa = ws + OFF_FAI_A;
  float* fb = ws + OFF_FAI_B;
  for (int it = 0; it < 8; ++it) {
    hipLaunchKernelGGL(k_giter, dim3(64), dim3(512), 0, stream, esr, eee, lamda, rk,
                       (it & 1) ? fb : fa, (it & 1) ? fa : fb, ws, it);
  }
  hipLaunchKernelGGL(k_gout, dim3(MM), dim3(512), 0, stream, me, ws, out);
}

// Round 4
// 994.739 us; speedup vs baseline: 4.8006x; 1.0596x over previous
//
#include <hip/hip_runtime.h>
#include <math.h>

#define MM 64
#define NN 512
#define DD 300
#define FF 768
#define CTXL 50
#define DOCL 100
#define BODYL 200
#define NHEAD 5
#define HD 60

typedef __attribute__((ext_vector_type(8))) short bf16x8;
typedef __attribute__((ext_vector_type(4))) float f32x4;
#define MFMA16(A,B,C) __builtin_amdgcn_mfma_f32_16x16x32_bf16(A,B,C,0,0,0)

__device__ __forceinline__ ushort f2bf(float f) {
  uint u = __float_as_uint(f);
  uint r = (u + 0x7FFFu + ((u >> 16) & 1u)) >> 16;   // RNE
  return (ushort)r;
}
__device__ __forceinline__ float bf2f(ushort h) {
  return __uint_as_float(((uint)h) << 16);
}

// ---------------- workspace layout (float offsets) ----------------
static constexpr size_t OFF_MS    = 0;                    // 64*768
static constexpr size_t OFF_MC    = 49152;                // 64*768
static constexpr size_t OFF_TNORM = 98304;                // 512
static constexpr size_t OFF_COSDT = 98816;                // 512
static constexpr size_t OFF_CAND  = 99328;                // 512*300
static constexpr size_t OFF_DOC   = 252928;               // 100*300
static constexpr size_t OFF_COMB  = 282928;               // 512*600
static constexpr size_t OFF_ATTS  = 590128;               // 512
static constexpr size_t OFF_COSST = 590640;               // 64*512
static constexpr size_t OFF_COSCT = 623408;               // 64*512
static constexpr size_t OFF_LOCATT= 656176;               // 64*512
static constexpr size_t OFF_S     = 688944;               // 512
static constexpr size_t OFF_KEEP  = 689456;               // 512
static constexpr size_t OFF_INV   = 689968;               // 512
static constexpr size_t OFF_FAI_A = 690480;               // 512
static constexpr size_t OFF_FAI_B = 690992;               // 512
static constexpr size_t OFF_CTXG  = 691504;               // 64*52*300
static constexpr size_t OFF_WT    = 1689904;              // 1500*768
static constexpr size_t OFF_DOCB  = 2841904;              // 5*112*64 bf16 = 17920 f
static constexpr size_t OFF_DOCT  = 2859824;              // 5*64*128 bf16 = 20480 f
static constexpr size_t OFF_CSQ   = 2880304;              // 5*64 f32
static constexpr size_t OFF_SRNT  = 2880624;              // 512*512 f32
// total 3142768 floats = 12.6 MB

// ---------------- init ----------------
__global__ __launch_bounds__(64) void k_init(
    const float* __restrict__ embed, const float* __restrict__ title,
    const float* __restrict__ bert, const int* __restrict__ cand_ids,
    const int* __restrict__ doc_ids, float* __restrict__ ws) {
  int n = blockIdx.x, t = threadIdx.x;
  float ss = 0.f, dd = 0.f, bb = 0.f;
  for (int j = t; j < FF; j += 64) {
    float tv = title[(size_t)n*FF + j], bv = bert[j];
    ss += tv*tv; dd += tv*bv; bb += bv*bv;
  }
#pragma unroll
  for (int o = 32; o; o >>= 1) {
    ss += __shfl_down(ss, o); dd += __shfl_down(dd, o); bb += __shfl_down(bb, o);
  }
  if (t == 0) {
    float tn = fmaxf(sqrtf(ss), 1e-6f);
    float bn = fmaxf(sqrtf(bb), 1e-6f);
    ws[OFF_TNORM + n] = tn;
    ws[OFF_COSDT + n] = dd / (tn * bn);
  }
  size_t cid = (size_t)cand_ids[n] * DD;
  for (int j = t; j < DD; j += 64) ws[OFF_CAND + (size_t)n*DD + j] = embed[cid + j];
  if (n < DOCL) {
    size_t did = (size_t)doc_ids[n] * DD;
    for (int j = t; j < DD; j += 64) ws[OFF_DOC + (size_t)n*DD + j] = embed[did + j];
  }
  if (n == 0) {
    for (int j = t; j < NN; j += 64) { ws[OFF_S + j] = 0.f; ws[OFF_KEEP + j] = 0.f; }
  }
}

// ---------------- doc fragments: docB[h][112][64], docT[h][64][128], csq ----
__global__ __launch_bounds__(256) void k_doc(float* __restrict__ ws) {
  int h = blockIdx.x, t = threadIdx.x;
  const float* doc = ws + OFF_DOC;
  ushort* docB = (ushort*)(ws + OFF_DOCB) + h*112*64;
  ushort* docT = (ushort*)(ws + OFF_DOCT) + h*64*128;
  for (int u = t; u < 112*8; u += 256) {
    int q = u >> 3, j8 = u & 7;
    uint pk[4] = {0,0,0,0};
    if (q < DOCL) {
#pragma unroll
      for (int i = 0; i < 8; ++i) {
        int j = j8*8 + i;
        float v = (j < HD) ? doc[q*DD + h*HD + j] : 0.f;
        pk[i>>1] |= ((uint)f2bf(v)) << ((i & 1) * 16);
      }
    }
    *(uint4*)&docB[q*64 + j8*8] = make_uint4(pk[0],pk[1],pk[2],pk[3]);
  }
  for (int u = t; u < 64*16; u += 256) {
    int d = u >> 4, q8 = u & 15;
    uint pk[4] = {0,0,0,0};
#pragma unroll
    for (int i = 0; i < 8; ++i) {
      int q = q8*8 + i;
      float v = 0.f;
      if (q < DOCL) {
        if (d < HD) v = doc[q*DD + h*HD + d];
        else if (d == HD) v = 1.f;              // ones row for colsum trick
      }
      pk[i>>1] |= ((uint)f2bf(v)) << ((i & 1) * 16);
    }
    *(uint4*)&docT[d*128 + q8*8] = make_uint4(pk[0],pk[1],pk[2],pk[3]);
  }
  if (t < 64) {
    float s = 0.f;
    if (t < HD) for (int q = 0; q < DOCL; ++q) s += bf2f(f2bf(doc[q*DD + h*HD + t]));
    ws[OFF_CSQ + h*64 + t] = s;
  }
}

// ---------------- gather ctx embeddings once ----------------
__global__ __launch_bounds__(256) void k_gather(
    const float* __restrict__ embed, const int* __restrict__ context_ids,
    float* __restrict__ ws) {
  int m = blockIdx.x, t = threadIdx.x;
  float* dst = ws + OFF_CTXG + (size_t)m*52*DD;
  for (int i = t; i < 52*DD; i += 256) {
    int r = i / DD, c = i - r*DD;
    dst[i] = (r < CTXL) ? embed[(size_t)context_ids[m*CTXL + r]*DD + c] : 0.f;
  }
}

// ---------------- transpose W_mc [f][d][k] -> Wt[k*300+d][f] ----------------
__global__ __launch_bounds__(256) void k_wt(
    const float* __restrict__ W, float* __restrict__ ws) {
  int kd = blockIdx.x;
  int k = kd / DD, d = kd - k*DD;
  int t = threadIdx.x;
  float* dst = ws + OFF_WT + (size_t)kd*FF;
  for (int f = t; f < FF; f += 256) dst[f] = W[(size_t)f*(DD*5) + d*5 + k];
}

// ---------------- mention surface conv ----------
__global__ __launch_bounds__(256) void k_ms(
    const float* __restrict__ embed, const int* __restrict__ mention_ids,
    const float* __restrict__ W, const float* __restrict__ b, float* __restrict__ ws) {
  __shared__ float x[4][DD];
  int m = blockIdx.x, t = threadIdx.x;
  for (int i = t; i < 4*DD; i += 256) {
    int r = i / DD, c = i % DD;
    x[r][c] = embed[(size_t)mention_ids[m*4 + r]*DD + c];
  }
  __syncthreads();
  for (int f = t; f < FF; f += 256) {
    const float* w = W + (size_t)f * (DD*2);
    float bb = b[f];
    float acc = 0.f;
#pragma unroll
    for (int tt = 0; tt < 3; ++tt) {
      float y = bb;
      for (int d = 0; d < DD; ++d) {
        float2 wv = *(const float2*)&w[d*2];
        y += wv.x * x[tt][d] + wv.y * x[tt+1][d];
      }
      acc += fmaxf(y, 0.f);
    }
    ws[OFF_MS + (size_t)m*FF + f] = acc * (1.f/3.f);
  }
}

// ---------------- context conv as tiled GEMM, BN=64 -> 768 blocks -----------
__global__ __launch_bounds__(256) void k_mc_gemm(
    const float* __restrict__ b_mc, float* __restrict__ ws) {
  __shared__ float As[50][49];
  __shared__ float Bs[50][64];
  int m = blockIdx.x, f0 = blockIdx.y * 64, t = threadIdx.x;
  int tr = t >> 4, tc = t & 15;
  const float* ctxm = ws + OFF_CTXG + (size_t)m*52*DD;
  const float4* wt4 = (const float4*)(ws + OFF_WT);
  float acc[3][4];
#pragma unroll
  for (int r = 0; r < 3; ++r)
#pragma unroll
    for (int j = 0; j < 4; ++j) acc[r][j] = 0.f;

  for (int chunk = 0; chunk < 30; ++chunk) {
    int k = chunk / 6, dc = (chunk - k*6) * 50;
    for (int i = t; i < 48*50; i += 256) {
      int row = i / 50, kj = i - row*50;
      As[kj][row] = ctxm[(row + k)*DD + dc + kj];
    }
    for (int i = t; i < 800; i += 256) {
      int kj = i >> 4, fq = i & 15;
      *(float4*)&Bs[kj][fq*4] = wt4[((size_t)(k*DD + dc + kj)*FF + f0 + fq*4) >> 2];
    }
    __syncthreads();
#pragma unroll 2
    for (int kj = 0; kj < 50; ++kj) {
      float a0 = As[kj][tr], a1 = As[kj][tr+16], a2 = As[kj][tr+32];
      float4 b0 = *(const float4*)&Bs[kj][tc*4];
      float bb[4] = {b0.x,b0.y,b0.z,b0.w};
#pragma unroll
      for (int j = 0; j < 4; ++j) {
        acc[0][j] += a0*bb[j]; acc[1][j] += a1*bb[j]; acc[2][j] += a2*bb[j];
      }
    }
    __syncthreads();
  }
  float bv[4], p[4];
#pragma unroll
  for (int j = 0; j < 4; ++j) { bv[j] = b_mc[f0 + tc*4 + j]; p[j] = 0.f; }
#pragma unroll
  for (int rr = 0; rr < 3; ++rr) {
    int row = tr + 16*rr;
    if (row < 46) {
#pragma unroll
      for (int j = 0; j < 4; ++j) p[j] += fmaxf(acc[rr][j] + bv[j], 0.f);
    }
  }
  float* red = &As[0][0];
#pragma unroll
  for (int j = 0; j < 4; ++j) red[tr*64 + tc*4 + j] = p[j];
  __syncthreads();
  if (t < 64) {
    float s = 0.f;
#pragma unroll
    for (int i = 0; i < 16; ++i) s += red[i*64 + t];
    ws[OFF_MC + (size_t)m*FF + f0 + t] = s * (1.f/46.f);
  }
}

// ---------------- cos_st / cos_ct ----------------
__global__ __launch_bounds__(256) void k_cos(
    const float* __restrict__ title, float* __restrict__ ws) {
  __shared__ float a[FF], bv_[FF];
  __shared__ float redA[4], redB[4];
  int m = blockIdx.x, t = threadIdx.x;
  float pa = 0.f, pb = 0.f;
  for (int j = t; j < FF; j += 256) {
    float v = ws[OFF_MS + (size_t)m*FF + j]; a[j] = v; pa += v*v;
    float u = ws[OFF_MC + (size_t)m*FF + j]; bv_[j] = u; pb += u*u;
  }
#pragma unroll
  for (int o = 32; o; o >>= 1) { pa += __shfl_down(pa, o); pb += __shfl_down(pb, o); }
  if ((t & 63) == 0) { redA[t>>6] = pa; redB[t>>6] = pb; }
  __syncthreads();
  float na = fmaxf(sqrtf(redA[0]+redA[1]+redA[2]+redA[3]), 1e-6f);
  float nb = fmaxf(sqrtf(redB[0]+redB[1]+redB[2]+redB[3]), 1e-6f);
  float ia = 1.f / na, ib = 1.f / nb;
  for (int n = t; n < NN; n += 256) {
    const float4* tr = (const float4*)(title + (size_t)n*FF);
    float ds = 0.f, dc = 0.f;
    for (int j = 0; j < FF/4; ++j) {
      float4 tv = tr[j];
      float4 av = *(const float4*)&a[j*4];
      float4 bw = *(const float4*)&bv_[j*4];
      ds += av.x*tv.x + av.y*tv.y + av.z*tv.z + av.w*tv.w;
      dc += bw.x*tv.x + bw.y*tv.y + bw.z*tv.z + bw.w*tv.w;
    }
    float it = 1.f / ws[OFF_TNORM + n];
    ws[OFF_COSST + (size_t)m*NN + n] = ds * ia * it;
    ws[OFF_COSCT + (size_t)m*NN + n] = dc * ib * it;
  }
}

// ============ 5-head doc<->body attention, MFMA, ones-row sum tricks ========
__global__ __launch_bounds__(256) void k_att(
    const float* __restrict__ embed, const int* __restrict__ body_ids,
    float* __restrict__ ws) {
  __shared__ __align__(16) ushort khB[224*64];   // [k][8 slots of 8], slot^(k&7)
  __shared__ __align__(16) ushort khT[64*232];   // [d][kk], row 60 = ones(k<200)
  __shared__ __align__(16) ushort XA[112*56];    // [q][kk 0..31], row 100 = ones
  __shared__ __align__(16) ushort XT[32*128];    // [kk][q], 16B-slot ^(kk&7)
  __shared__ float rs_l[112];
  __shared__ float cs_c[32];

  const float SCALE = 0.1290994448735806f; // 1/sqrt(60)
  int n = blockIdx.x, h = blockIdx.y, t = threadIdx.x;
  int w = t >> 6, l = t & 63;
  int l15 = l & 15, l4 = l >> 4;
  const int* bids = body_ids + n*BODYL;
  const ushort* docB = (const ushort*)(ws + OFF_DOCB) + h*112*64;
  const ushort* docT = (const ushort*)(ws + OFF_DOCT) + h*64*128;
  int dcol = 16*w + l15;
  float csq_r = ws[OFF_CSQ + h*64 + dcol];

  // stage khB (coalesced gather, swizzled uint4 LDS writes)
  for (int u = t; u < 224*8; u += 256) {
    int k = u >> 3, j8 = u & 7;
    uint pk[4] = {0,0,0,0};
    if (k < BODYL) {
      const float* src = embed + (size_t)bids[k]*DD + h*HD;
      float4 v0 = *(const float4*)&src[j8*8];
      float4 v1 = {0.f,0.f,0.f,0.f};
      if (j8 < 7) v1 = *(const float4*)&src[j8*8+4];
      pk[0] = (uint)f2bf(v0.x) | ((uint)f2bf(v0.y) << 16);
      pk[1] = (uint)f2bf(v0.z) | ((uint)f2bf(v0.w) << 16);
      pk[2] = (uint)f2bf(v1.x) | ((uint)f2bf(v1.y) << 16);
      pk[3] = (uint)f2bf(v1.z) | ((uint)f2bf(v1.w) << 16);
    }
    *(uint4*)&khB[k*64 + (j8 ^ (k & 7))*8] = make_uint4(pk[0],pk[1],pk[2],pk[3]);
  }
  // zero XT cols 112..127 (never written by P1)
  for (int u = t; u < 512; u += 256) {
    int kk = u >> 4, q = 112 + (u & 15);
    XT[kk*128 + ((q >> 3) ^ (kk & 7))*8 + (q & 7)] = 0;
  }
  __syncthreads();
  // khT[d][k] from khB; row 60 = ones(k<200); else-pad zero
  for (int v = t; v < 232*64; v += 256) {
    int d = v & 63, k = v >> 6;
    ushort val = 0;
    if (k < BODYL) {
      if (d < HD) val = khB[k*64 + ((d >> 3) ^ (k & 7))*8 + (d & 7)];
      else if (d == HD) val = 0x3F80;   // 1.0 bf16 -> rowsum trick
    }
    khT[d*232 + k] = val;
  }
  __syncthreads();

  f32x4 Cdb[7];
#pragma unroll
  for (int i = 0; i < 7; ++i) Cdb[i] = (f32x4){0.f,0.f,0.f,0.f};
  float bdmx = -1e30f, dbmx = -1e30f;

  // hoist docT fragments (constant across chunks)
  bf16x8 bfrT[4];
#pragma unroll
  for (int qs = 0; qs < 4; ++qs)
    bfrT[qs] = *(const bf16x8*)&docT[dcol*128 + qs*32 + l4*8];

  for (int c = 0; c < 7; ++c) {
    int k0 = c*32;
    // P1: S both orientations from one fragment pair -> XA + XT
    for (int task = w; task < 14; task += 4) {
      int mt = (task >= 7) ? 1 : 0;
      int nt = task - mt*7;
      int krow = k0 + 16*mt + l15;
      int qrow = 16*nt + l15;
      bf16x8 ka0 = *(const bf16x8*)&khB[krow*64 + ((0 + l4) ^ (krow & 7))*8];
      bf16x8 ka1 = *(const bf16x8*)&khB[krow*64 + ((4 + l4) ^ (krow & 7))*8];
      bf16x8 qa0 = *(const bf16x8*)&docB[qrow*64 + l4*8];
      bf16x8 qa1 = *(const bf16x8*)&docB[qrow*64 + 32 + l4*8];
      f32x4 d1 = (f32x4){0.f,0.f,0.f,0.f}, d1b = (f32x4){0.f,0.f,0.f,0.f};
      d1  = MFMA16(ka0, qa0, d1);  d1  = MFMA16(ka1, qa1, d1);
      d1b = MFMA16(qa0, ka0, d1b); d1b = MFMA16(qa1, ka1, d1b);
      {
        int kkb = 16*mt + 4*l4;
        ushort xs[4];
#pragma unroll
        for (int r = 0; r < 4; ++r) {
          int kg = k0 + kkb + r;
          float x = 0.f;
          if (qrow < DOCL) { if (kg < BODYL) x = __expf(d1[r]*SCALE) - 1.f; }
          else if (qrow == DOCL) { if (kg < BODYL) x = 1.f; }   // csk ones row
          xs[r] = f2bf(x);
        }
        uint2 wv = make_uint2((uint)xs[0] | ((uint)xs[1] << 16),
                              (uint)xs[2] | ((uint)xs[3] << 16));
        *(uint2*)&XA[qrow*56 + kkb] = wv;
      }
      {
        int kk = 16*mt + l15;
        int kg = k0 + kk;
        int q0 = 16*nt + 4*l4;
        ushort xs[4];
#pragma unroll
        for (int r = 0; r < 4; ++r) {
          int q = q0 + r;
          float x = (q < DOCL && kg < BODYL) ? (__expf(d1b[r]*SCALE) - 1.f) : 0.f;
          xs[r] = f2bf(x);
        }
        uint2 wv = make_uint2((uint)xs[0] | ((uint)xs[1] << 16),
                              (uint)xs[2] | ((uint)xs[3] << 16));
        *(uint2*)&XT[kk*128 + ((q0 >> 3) ^ (kk & 7))*8 + (q0 & 7)] = wv;
      }
    }
    __syncthreads();
    // P2: Cdb[q][d] += XA . khT  (col 60 accumulates rowsums rs)
    {
      bf16x8 bfr = *(const bf16x8*)&khT[dcol*232 + k0 + l4*8];
#pragma unroll
      for (int mt2 = 0; mt2 < 7; ++mt2) {
        bf16x8 afr = *(const bf16x8*)&XA[(16*mt2 + l15)*56 + l4*8];
        Cdb[mt2] = MFMA16(afr, bfr, Cdb[mt2]);
      }
    }
    // P2b: Cbd[k][d] = XT . docT  (col 60 = colsums cs)
    f32x4 a3[2];
#pragma unroll
    for (int kt = 0; kt < 2; ++kt) {
      int kkl = 16*kt + l15;
      f32x4 acc = (f32x4){0.f,0.f,0.f,0.f};
#pragma unroll
      for (int qs = 0; qs < 4; ++qs) {
        bf16x8 afr = *(const bf16x8*)&XT[kkl*128 + ((qs*4 + l4) ^ (kkl & 7))*8];
        acc = MFMA16(afr, bfrT[qs], acc);
      }
      a3[kt] = acc;
    }
    if (w == 3 && l15 == 12) {         // d == 60: publish cs
#pragma unroll
      for (int kt = 0; kt < 2; ++kt)
#pragma unroll
        for (int r = 0; r < 4; ++r)
          cs_c[16*kt + 4*l4 + r] = 100.f + a3[kt][r];
    }
    __syncthreads();
    // bd finalize for this chunk
#pragma unroll
    for (int kt = 0; kt < 2; ++kt) {
#pragma unroll
      for (int r = 0; r < 4; ++r) {
        int kk = 16*kt + 4*l4 + r;
        if (k0 + kk < BODYL) {
          float v = (csq_r + a3[kt][r]) / cs_c[kk];
          bdmx = fmaxf(bdmx, v);
        }
      }
    }
    __syncthreads();   // XA/XT consumed; safe to overwrite next chunk
  }

  // publish rs (col 60 of Cdb) and extract csk (row 100 of Cdb)
  if (w == 3 && l15 == 12) {
#pragma unroll
    for (int mt2 = 0; mt2 < 7; ++mt2)
#pragma unroll
      for (int r = 0; r < 4; ++r)
        rs_l[16*mt2 + 4*l4 + r] = Cdb[mt2][r];
  }
  float csk_r = __shfl(Cdb[6][0], 16 + l15);   // lane l4==1, r==0 holds q=100
  __syncthreads();
#pragma unroll
  for (int mt2 = 0; mt2 < 7; ++mt2) {
#pragma unroll
    for (int r = 0; r < 4; ++r) {
      int q = 16*mt2 + 4*l4 + r;
      if (q < DOCL) {
        float v = (csk_r + Cdb[mt2][r]) / (200.f + rs_l[q]);
        dbmx = fmaxf(dbmx, v);
      }
    }
  }
  dbmx = fmaxf(dbmx, __shfl_xor(dbmx, 16));
  dbmx = fmaxf(dbmx, __shfl_xor(dbmx, 32));
  bdmx = fmaxf(bdmx, __shfl_xor(bdmx, 16));
  bdmx = fmaxf(bdmx, __shfl_xor(bdmx, 32));
  if (l4 == 0 && dcol < HD) {
    ws[OFF_COMB + (size_t)n*600 + h*HD + dcol] = dbmx;
    ws[OFF_COMB + (size_t)n*600 + 300 + h*HD + dcol] = bdmx;
  }
}

// ---------------- local context attention ----------------
__global__ __launch_bounds__(256) void k_local(
    float* __restrict__ ws) {
  __shared__ __align__(16) float x[CTXL][304];
  __shared__ float red[2][128];
  int m = blockIdx.x, nc = blockIdx.y, t = threadIdx.x;
  const float* ctxm = ws + OFF_CTXG + (size_t)m*52*DD;
  for (int i = t; i < CTXL*DD; i += 256) {
    int r = i / DD, c = i % DD;
    x[r][c] = ctxm[i];
  }
  __syncthreads();
  int nl = t & 127, half = t >> 7;
  int n = nc*128 + nl;
  const float4* cr = (const float4*)(ws + OFF_CAND + (size_t)n*DD);
  float acc[25];
#pragma unroll
  for (int i = 0; i < 25; ++i) acc[i] = 0.f;
  for (int d4 = 0; d4 < 75; ++d4) {
    float4 cv = cr[d4];
#pragma unroll
    for (int i = 0; i < 25; ++i) {
      float4 xv = *(const float4*)&x[half*25 + i][d4*4];
      acc[i] += xv.x*cv.x + xv.y*cv.y + xv.z*cv.z + xv.w*cv.w;
    }
  }
  float mx = -1e30f;
#pragma unroll
  for (int i = 0; i < 25; ++i) mx = fmaxf(mx, acc[i]);
  red[half][nl] = mx;
  __syncthreads();
  if (t < 128) {
    float v = fmaxf(red[0][t], red[1][t]) * 0.05773502691896258f;
    ws[OFF_LOCATT + (size_t)m*NN + nc*128 + t] = v;
  }
}

// ---------------- attention MLP -> att_score ----------------
__global__ __launch_bounds__(256) void k_mlp(
    const float* __restrict__ W1, const float* __restrict__ b1,
    const float* __restrict__ W2, const float* __restrict__ b2,
    float* __restrict__ ws) {
  __shared__ float comb8[8][600];
  __shared__ float acc8[8];
  int b = blockIdx.x, t = threadIdx.x;
  int n0 = b*8;
  for (int i = t; i < 8*600; i += 256)
    comb8[i/600][i%600] = ws[OFF_COMB + (size_t)(n0 + i/600)*600 + (i%600)];
  if (t < 8) acc8[t] = 0.f;
  __syncthreads();
  float psum[8];
#pragma unroll
  for (int nn2 = 0; nn2 < 8; ++nn2) psum[nn2] = 0.f;
  for (int j = t; j < 300; j += 256) {
    float hh[8];
#pragma unroll
    for (int nn2 = 0; nn2 < 8; ++nn2) hh[nn2] = b1[j];
    for (int i = 0; i < 600; ++i) {
      float w = W1[(size_t)i*300 + j];
#pragma unroll
      for (int nn2 = 0; nn2 < 8; ++nn2) hh[nn2] += comb8[nn2][i]*w;
    }
    float w2 = W2[j];
#pragma unroll
    for (int nn2 = 0; nn2 < 8; ++nn2) psum[nn2] += fmaxf(hh[nn2], 0.f)*w2;
  }
#pragma unroll
  for (int nn2 = 0; nn2 < 8; ++nn2) atomicAdd(&acc8[nn2], psum[nn2]);
  __syncthreads();
  if (t < 8) {
    float v = acc8[t] + b2[0];
    ws[OFF_ATTS + n0 + t] = 1.f / (1.f + __expf(-v));
  }
}

// ---------------- per-mention scoring ----------------
__device__ __forceinline__ float bsum512(float v, float* red) {
  int t = threadIdx.x;
#pragma unroll
  for (int o = 32; o; o >>= 1) v += __shfl_down(v, o);
  __syncthreads();
  if ((t & 63) == 0) red[t>>6] = v;
  __syncthreads();
  float s = 0.f;
#pragma unroll
  for (int i = 0; i < 8; ++i) s += red[i];
  return s;
}
__device__ __forceinline__ float bmax512(float v, float* red) {
  int t = threadIdx.x;
#pragma unroll
  for (int o = 32; o; o >>= 1) v = fmaxf(v, __shfl_down(v, o));
  __syncthreads();
  if ((t & 63) == 0) red[t>>6] = v;
  __syncthreads();
  float s = -INFINITY;
#pragma unroll
  for (int i = 0; i < 8; ++i) s = fmaxf(s, red[i]);
  return s;
}

__global__ __launch_bounds__(512) void k_score(
    const float* __restrict__ hand, const float* __restrict__ m2c,
    const float* __restrict__ llW, const float* __restrict__ llb,
    const float* __restrict__ me, float* __restrict__ ws) {
  __shared__ float red[8];
  __shared__ float rv[512];
  __shared__ int ri[512];
  int m = blockIdx.x, t = threadIdx.x;
  float mask = me[(size_t)m*NN + t];
  float raw = llW[0]*hand[t] + llW[1]*m2c[t] + llW[2]*ws[OFF_LOCATT + (size_t)m*NN + t]
            + llW[3]*ws[OFF_ATTS + t] + llW[4]*ws[OFF_COSST + (size_t)m*NN + t]
            + llW[5]*ws[OFF_COSDT + t] + llW[6]*ws[OFF_COSCT + (size_t)m*NN + t] + llb[0];
  float cnt = bsum512(mask, red);
  float mean = bsum512(raw*mask, red) / cnt;
  float dv = raw - mean;
  float var = bsum512(dv*dv*mask, red) / (cnt - 1.f);
  float z = dv / sqrtf(var);
  float zm = (mask > 0.f) ? z : -INFINITY;
  float mx = bmax512(zm, red);
  float e = (mask > 0.f) ? __expf(zm - mx) : 0.f;
  float ssum = bsum512(e, red);
  float sm = e / ssum * mask;
  atomicAdd(&ws[OFF_S + t], sm);
  bool excl = false;
  for (int r = 0; r < 3; ++r) {
    rv[t] = excl ? -INFINITY : zm;
    ri[t] = t;
    __syncthreads();
    for (int off = 256; off; off >>= 1) {
      if (t < off) {
        float bb = rv[t+off]; int ib = ri[t+off];
        if (bb > rv[t] || (bb == rv[t] && ib < ri[t])) { rv[t] = bb; ri[t] = ib; }
      }
      __syncthreads();
    }
    int widx = ri[0];
    __syncthreads();
    if (t == 0) ws[OFF_KEEP + widx] = 1.f;
    if (t == widx) excl = true;
  }
}

// ---------------- SR row sums -> inv, init fai = s ----------------
__global__ __launch_bounds__(512) void k_grs(
    const float* __restrict__ esr, const float* __restrict__ eee,
    float* __restrict__ ws) {
  __shared__ float keep_l[NN];
  int b = blockIdx.x, t = threadIdx.x;
  keep_l[t] = ws[OFF_KEEP + t];
  __syncthreads();
  int lane = t & 63, w = t >> 6;
  int r = b*8 + w;
  float p = 0.f;
  for (int j = lane; j < NN; j += 64)
    p += esr[(size_t)r*NN + j] * eee[(size_t)r*NN + j] * keep_l[j];
#pragma unroll
  for (int o = 32; o; o >>= 1) p += __shfl_down(p, o);
  if (lane == 0) {
    ws[OFF_INV + r] = (fabsf(p) < 1e-6f) ? 1.f : 1.f/p;
    ws[OFF_FAI_A + r] = ws[OFF_S + r];
  }
}

// ---------------- SRnT[j][i] = SR[i][j] (normalized, keep folded) -----------
__global__ __launch_bounds__(256) void k_srt(
    const float* __restrict__ esr, const float* __restrict__ eee,
    float* __restrict__ ws) {
  int j = blockIdx.x, t = threadIdx.x;
  float kj = ws[OFF_KEEP + j];
  float* dst = ws + OFF_SRNT + (size_t)j*NN;
  for (int i = t; i < NN; i += 256)
    dst[i] = esr[(size_t)i*NN + j] * eee[(size_t)i*NN + j] * kj * ws[OFF_INV + i];
}

// ---------------- one power-iteration step (coalesced, 512 blocks) ----------
__global__ __launch_bounds__(256) void k_giter(
    const float* __restrict__ lamda, const int* __restrict__ rk,
    const float* __restrict__ fin, float* __restrict__ fout,
    const float* __restrict__ wsro, int it) {
  int j = blockIdx.x, t = threadIdx.x;
  if (it >= rk[0]) { if (t == 0) fout[j] = fin[j]; return; }
  __shared__ float red[4];
  const float* srn = wsro + OFF_SRNT + (size_t)j*NN;
  float p = fin[t]*srn[t] + fin[t+256]*srn[t+256];
#pragma unroll
  for (int o = 32; o; o >>= 1) p += __shfl_down(p, o);
  if ((t & 63) == 0) red[t>>6] = p;
  __syncthreads();
  if (t == 0) {
    float lam = lamda[0];
    fout[j] = (1.f - lam)*(red[0]+red[1]+red[2]+red[3]) + lam*wsro[OFF_S + j];
  }
}

// ---------------- final outputs ----------------
__global__ __launch_bounds__(512) void k_gout(
    const float* __restrict__ me, const float* __restrict__ ws, float* __restrict__ out) {
  int m = blockIdx.x, t = threadIdx.x;
  float fai = ws[OFF_FAI_A + t];
  if (m == 0) { out[t] = ws[OFF_S + t]; out[NN + t] = fai; }
  out[2*NN + (size_t)m*NN + t] = me[(size_t)m*NN + t] * fai;
}

extern "C" void kernel_launch(void* const* d_in, const int* in_sizes, int n_in,
                              void* d_out, int out_size, void* d_ws, size_t ws_size,
                              hipStream_t stream) {
  const float* embed   = (const float*)d_in[0];
  const float* W_ms    = (const float*)d_in[1];
  const float* b_ms    = (const float*)d_in[2];
  const float* W_mc    = (const float*)d_in[3];
  const float* b_mc    = (const float*)d_in[4];
  const float* att_W1  = (const float*)d_in[5];
  const float* att_b1  = (const float*)d_in[6];
  const float* att_W2  = (const float*)d_in[7];
  const float* att_b2  = (const float*)d_in[8];
  const float* ll_W    = (const float*)d_in[9];
  const float* ll_b    = (const float*)d_in[10];
  const float* lamda   = (const float*)d_in[11];
  const int* mention_ids = (const int*)d_in[12];
  const int* context_ids = (const int*)d_in[13];
  const int* doc_ids     = (const int*)d_in[14];
  const int* body_ids    = (const int*)d_in[15];
  const int* cand_ids    = (const int*)d_in[16];
  const float* title   = (const float*)d_in[17];
  const float* bert    = (const float*)d_in[18];
  const float* hand    = (const float*)d_in[19];
  const float* m2c     = (const float*)d_in[20];
  const float* me      = (const float*)d_in[21];
  const float* eee     = (const float*)d_in[22];
  const float* esr     = (const float*)d_in[23];
  const int* rk        = (const int*)d_in[24];
  float* ws  = (float*)d_ws;
  float* out = (float*)d_out;

  hipLaunchKernelGGL(k_init, dim3(NN), dim3(64), 0, stream, embed, title, bert, cand_ids, doc_ids, ws);
  hipLaunchKernelGGL(k_doc, dim3(NHEAD), dim3(256), 0, stream, ws);
  hipLaunchKernelGGL(k_gather, dim3(MM), dim3(256), 0, stream, embed, context_ids, ws);
  hipLaunchKernelGGL(k_wt, dim3(1500), dim3(256), 0, stream, W_mc, ws);
  hipLaunchKernelGGL(k_ms, dim3(MM), dim3(256), 0, stream, embed, mention_ids, W_ms, b_ms, ws);
  hipLaunchKernelGGL(k_mc_gemm, dim3(MM, 12), dim3(256), 0, stream, b_mc, ws);
  hipLaunchKernelGGL(k_cos, dim3(MM), dim3(256), 0, stream, title, ws);
  hipLaunchKernelGGL(k_att, dim3(NN, NHEAD), dim3(256), 0, stream, embed, body_ids, ws);
  hipLaunchKernelGGL(k_local, dim3(MM, 4), dim3(256), 0, stream, ws);
  hipLaunchKernelGGL(k_mlp, dim3(64), dim3(256), 0, stream, att_W1, att_b1, att_W2, att_b2, ws);
  hipLaunchKernelGGL(k_score, dim3(MM), dim3(512), 0, stream, hand, m2c, ll_W, ll_b, me, ws);
  hipLaunchKernelGGL(k_grs, dim3(64), dim3(512), 0, stream, esr, eee, ws);
  hipLaunchKernelGGL(k_srt, dim3(NN), dim3(256), 0, stream, esr, eee, ws);
  float* fa = ws + OFF_FAI_A;
  float* fb = ws + OFF_FAI_B;
  for (int it = 0; it < 8; ++it) {
    hipLaunchKernelGGL(k_giter, dim3(NN), dim3(256), 0, stream, lamda, rk,
                       (it & 1) ? fb : fa, (it & 1) ? fa : fb, ws, it);
  }
  hipLaunchKernelGGL(k_gout, dim3(MM), dim3(512), 0, stream, me, ws, out);
}